// Round 7
// baseline (857.398 us; speedup 1.0000x reference)
//
#include <hip/hip_runtime.h>
#include <hip/hip_fp16.h>
#include <cstddef>
#include <cstdint>

constexpr int DIMS = 128;
constexpr float BN_EPS = 1e-5f;
constexpr int NSH = 64;   // stat shadow copies
constexpr int GB = 2048;  // gather grid blocks (x4 waves = 8192 waves)

typedef _Float16 f16x8 __attribute__((ext_vector_type(8)));
typedef float f32x4 __attribute__((ext_vector_type(4)));

static __device__ __forceinline__ f16x8 as_f16x8(uint4 u) {
  union { uint4 u; f16x8 h; } x; x.u = u; return x.h;
}
static __device__ __forceinline__ __half2 as_h2(uint32_t u) {
  union { uint32_t u; __half2 h; } x; x.u = u; return x.h;
}

// ---------------- utility ----------------
__global__ void zero_k(int* __restrict__ ip, size_t ni, float* __restrict__ fp, size_t nf) {
  size_t i = (size_t)blockIdx.x * blockDim.x + threadIdx.x;
  if (i < ni) ip[i] = 0;
  if (i < nf) fp[i] = 0.f;
}

// fp32 -> fp16 conversion with dn pre-scale (dn computed inline from deg):
// Xp[s] = dn[s] * nfeat[s];  also writes dnorm[s]
__global__ void cvt_k(const float* __restrict__ in, uint32_t* __restrict__ out,
                      const int* __restrict__ deg, float* __restrict__ dnorm, size_t n64) {
  size_t i = (size_t)blockIdx.x * blockDim.x + threadIdx.x;
  size_t stride = (size_t)gridDim.x * blockDim.x;
  const float2* in2 = (const float2*)in;
  for (; i < n64; i += stride) {
    size_t row = i >> 6;
    float d = rsqrtf(fmaxf((float)deg[row], 1.0f));
    if ((i & 63) == 0) dnorm[row] = d;
    float2 v = in2[i];
    __half2 h = __floats2half2_rn(v.x * d, v.y * d);
    out[i] = *(const uint32_t*)&h;
  }
}

// ---------------- binned CSR build (kills scatter write-amplification) -------------
// bins of 512 nodes; nbins <= 512 assumed (n <= 262144)

__global__ void bin_count_k(const int* __restrict__ dst, int* __restrict__ bcnt,
                            int e, int nbins) {
  __shared__ int hist[512];
  for (int i = threadIdx.x; i < nbins; i += 256) hist[i] = 0;
  __syncthreads();
  for (int i = blockIdx.x * 256 + threadIdx.x; i < e; i += gridDim.x * 256)
    atomicAdd(&hist[dst[i] >> 9], 1);
  __syncthreads();
  for (int i = threadIdx.x; i < nbins; i += 256)
    if (hist[i]) atomicAdd(&bcnt[i], hist[i]);
}

__global__ void bin_scan_k(const int* __restrict__ bcnt, int nbins,
                           int* __restrict__ boff, int* __restrict__ gcur, int e) {
  __shared__ int lds[512];
  int t = threadIdx.x;
  int v = (t < nbins) ? bcnt[t] : 0;
  lds[t] = v; __syncthreads();
  for (int off = 1; off < 512; off <<= 1) {
    int add = (t >= off) ? lds[t - off] : 0;
    __syncthreads();
    lds[t] += add;
    __syncthreads();
  }
  if (t < nbins) { boff[t] = lds[t] - v; gcur[t] = 0; }
  if (t == 0) boff[nbins] = e;
}

// ebin[boff[b]+p] = (src<<9) | (dst&511)   (src < 2^18, fits 27 bits)
__global__ void bin_scatter_k(const int* __restrict__ src, const int* __restrict__ dst,
                              const int* __restrict__ boff, int* __restrict__ gcur,
                              int* __restrict__ ebin, int e) {
  int i = blockIdx.x * 256 + threadIdx.x;
  int stride = gridDim.x * 256;
  for (; i < e; i += stride) {
    int d = dst[i];
    int b = d >> 9;
    int p = atomicAdd(&gcur[b], 1);
    ebin[boff[b] + p] = (src[i] << 9) | (d & 511);
  }
}

// per-node degree via LDS counters (no global atomics)
__global__ void deg_bins_k(const int* __restrict__ ebin, const int* __restrict__ boff,
                           int* __restrict__ deg, int n) {
  __shared__ int cnt[512];
  int b = blockIdx.x;
  for (int j = threadIdx.x; j < 512; j += 256) cnt[j] = 0;
  __syncthreads();
  int j0 = boff[b], j1 = boff[b + 1];
  for (int i = j0 + threadIdx.x; i < j1; i += 256) atomicAdd(&cnt[ebin[i] & 511], 1);
  __syncthreads();
  int base = b << 9;
  for (int j = threadIdx.x; j < 512; j += 256) {
    int node = base + j;
    if (node < n) deg[node] = cnt[j];
  }
}

// ---------------- CSR scan over degrees (row_off) ----------------
__global__ void scan1_k(const int* __restrict__ deg, int* __restrict__ bsum, int n) {
  __shared__ int lds[256];
  int t = threadIdx.x;
  int base = blockIdx.x * 1024;
  int s = 0;
  for (int i = t; i < 1024; i += 256) {
    int idx = base + i;
    s += (idx < n) ? deg[idx] : 0;
  }
  lds[t] = s; __syncthreads();
  for (int off = 128; off > 0; off >>= 1) {
    if (t < off) lds[t] += lds[t + off];
    __syncthreads();
  }
  if (t == 0) bsum[blockIdx.x] = lds[0];
}

__global__ void scan2_k(int* __restrict__ bsum, int nb, int* __restrict__ row_off, int n, int e) {
  __shared__ int lds[256];
  int t = threadIdx.x;
  int v = (t < nb) ? bsum[t] : 0;
  lds[t] = v; __syncthreads();
  for (int off = 1; off < 256; off <<= 1) {
    int add = (t >= off) ? lds[t - off] : 0;
    __syncthreads();
    lds[t] += add;
    __syncthreads();
  }
  if (t < nb) bsum[t] = lds[t] - v;  // exclusive base per chunk
  if (t == 0) row_off[n] = e;
}

__global__ void scan3_k(const int* __restrict__ deg, const int* __restrict__ bsum,
                        int* __restrict__ row_off, int n) {
  __shared__ int lds[256];
  int t = threadIdx.x;
  int base = blockIdx.x * 1024 + t * 4;
  int e0 = (base + 0 < n) ? deg[base + 0] : 0;
  int e1 = (base + 1 < n) ? deg[base + 1] : 0;
  int e2 = (base + 2 < n) ? deg[base + 2] : 0;
  int e3 = (base + 3 < n) ? deg[base + 3] : 0;
  int ts = e0 + e1 + e2 + e3;
  lds[t] = ts; __syncthreads();
  for (int off = 1; off < 256; off <<= 1) {
    int add = (t >= off) ? lds[t - off] : 0;
    __syncthreads();
    lds[t] += add;
    __syncthreads();
  }
  int ex = lds[t] - ts + bsum[blockIdx.x];
  if (base + 0 < n) row_off[base + 0] = ex;
  ex += e0;
  if (base + 1 < n) row_off[base + 1] = ex;
  ex += e1;
  if (base + 2 < n) row_off[base + 2] = ex;
  ex += e2;
  if (base + 3 < n) row_off[base + 3] = ex;
}

// adj placement: all writes fall in the bin's contiguous adj region (L2-hot)
__global__ void adj_bins_k(const int* __restrict__ ebin, const int* __restrict__ boff,
                           const int* __restrict__ row_off, int* __restrict__ adj, int n) {
  __shared__ int cur[512];
  __shared__ int ro[512];
  int b = blockIdx.x;
  int base = b << 9;
  for (int j = threadIdx.x; j < 512; j += 256) {
    cur[j] = 0;
    int node = base + j;
    ro[j] = (node < n) ? row_off[node] : 0;
  }
  __syncthreads();
  int j0 = boff[b], j1 = boff[b + 1];
  for (int i = j0 + threadIdx.x; i < j1; i += 256) {
    int pk = ebin[i];
    int dl = pk & 511;
    int s = pk >> 9;
    int p = atomicAdd(&cur[dl], 1);
    adj[ro[dl] + p] = s;
  }
}

// ---------------- propagation hop: grid-stride, TWO nodes per wave in flight -------
// Lane owns 2 features (half2 row element). 8-deep edge pipeline per node stream.
// AFF=false (hop1): acc = sum Xp[s]; v = dn*acc (stats); store W1 = dn^2*acc;
//                   also wsum[node] = sum dn[s] (computed inline, lane 0 writes).
// AFF=true  (hop2): acc = sum W1[s]; v = dn*(a*acc + b*wsum[n]) (stats); store v.
template <bool AFF>
__global__ __launch_bounds__(256) void gather_k(
    const uint32_t* __restrict__ Xu, uint32_t* __restrict__ Yout,
    const int* __restrict__ row_off, const int* __restrict__ adj,
    const float* __restrict__ dn, float* __restrict__ wsum,
    const float* __restrict__ a, const float* __restrict__ b,
    float* __restrict__ sumS, float* __restrict__ sqS, int n, int nwaves) {
  int tid = threadIdx.x;
  int l = tid & 63, w = tid >> 6;
  int wid = blockIdx.x * 4 + w;  // wave-uniform
  uint32_t lu = (uint32_t)l;
  int f0 = 2 * l;
  float af0 = 1.f, bf0 = 0.f, af1 = 1.f, bf1 = 0.f;
  if (AFF) { af0 = a[f0]; bf0 = b[f0]; af1 = a[f0 + 1]; bf1 = b[f0 + 1]; }
  float s0 = 0.f, s1 = 0.f, q0 = 0.f, q1 = 0.f;

  for (int nodeA = wid; nodeA < n; nodeA += 2 * nwaves) {
    const int nodeB = nodeA + nwaves;
    const bool hasB = nodeB < n;
    int ja = row_off[nodeA];
    const int ea = row_off[nodeA + 1];
    int jb = hasB ? row_off[nodeB] : 0;
    const int eb = hasB ? row_off[nodeB + 1] : 0;
    float accA0 = 0.f, accA1 = 0.f, accB0 = 0.f, accB1 = 0.f;
    float dsA = 0.f, dsB = 0.f;

    while ((ja < ea) || (jb < eb)) {
      uint32_t xa[8], xb[8];
      float da[8], db[8];
      const bool runA = ja < ea, runB = jb < eb;
      if (runA) {  // issue 8 loads for stream A
#pragma unroll
        for (int t = 0; t < 8; ++t) {
          int jj = ja + t;
          int jc = jj < ea ? jj : ea - 1;
          uint32_t sj = (uint32_t)adj[jc];
          uint32_t v = Xu[(sj << 6) + lu];
          xa[t] = (jj < ea) ? v : 0u;
          if constexpr (!AFF) {
            float dv = dn[sj];
            da[t] = (jj < ea) ? dv : 0.f;
          }
        }
      }
      if (runB) {  // issue 8 more (independent -> 16 in flight)
#pragma unroll
        for (int t = 0; t < 8; ++t) {
          int jj = jb + t;
          int jc = jj < eb ? jj : eb - 1;
          uint32_t sj = (uint32_t)adj[jc];
          uint32_t v = Xu[(sj << 6) + lu];
          xb[t] = (jj < eb) ? v : 0u;
          if constexpr (!AFF) {
            float dv = dn[sj];
            db[t] = (jj < eb) ? dv : 0.f;
          }
        }
      }
      if (runA) {  // depth-2 fp16 pairwise tree, fp32 accumulate
        __half2 t0 = __hadd2(as_h2(xa[0]), as_h2(xa[1]));
        __half2 t1 = __hadd2(as_h2(xa[2]), as_h2(xa[3]));
        __half2 t2 = __hadd2(as_h2(xa[4]), as_h2(xa[5]));
        __half2 t3 = __hadd2(as_h2(xa[6]), as_h2(xa[7]));
        float2 u0 = __half22float2(__hadd2(t0, t1));
        float2 u1 = __half22float2(__hadd2(t2, t3));
        accA0 += u0.x + u1.x;
        accA1 += u0.y + u1.y;
        if constexpr (!AFF)
          dsA += ((da[0] + da[1]) + (da[2] + da[3])) + ((da[4] + da[5]) + (da[6] + da[7]));
        ja += 8;
      }
      if (runB) {
        __half2 t0 = __hadd2(as_h2(xb[0]), as_h2(xb[1]));
        __half2 t1 = __hadd2(as_h2(xb[2]), as_h2(xb[3]));
        __half2 t2 = __hadd2(as_h2(xb[4]), as_h2(xb[5]));
        __half2 t3 = __hadd2(as_h2(xb[6]), as_h2(xb[7]));
        float2 u0 = __half22float2(__hadd2(t0, t1));
        float2 u1 = __half22float2(__hadd2(t2, t3));
        accB0 += u0.x + u1.x;
        accB1 += u0.y + u1.y;
        if constexpr (!AFF)
          dsB += ((db[0] + db[1]) + (db[2] + db[3])) + ((db[4] + db[5]) + (db[6] + db[7]));
        jb += 8;
      }
    }

    {  // finalize node A
      float dnn = dn[nodeA];
      float v0, v1;
      if constexpr (AFF) {
        float wsn = wsum[nodeA];
        v0 = dnn * fmaf(af0, accA0, bf0 * wsn);
        v1 = dnn * fmaf(af1, accA1, bf1 * wsn);
        __half2 hv = __floats2half2_rn(v0, v1);
        Yout[((uint32_t)nodeA << 6) + lu] = *(const uint32_t*)&hv;
      } else {
        v0 = dnn * accA0;
        v1 = dnn * accA1;
        __half2 hv = __floats2half2_rn(v0 * dnn, v1 * dnn);  // W1 = dn^2*acc
        Yout[((uint32_t)nodeA << 6) + lu] = *(const uint32_t*)&hv;
        if (l == 0) wsum[nodeA] = dsA;
      }
      s0 += v0; s1 += v1; q0 += v0 * v0; q1 += v1 * v1;
    }
    if (hasB) {  // finalize node B
      float dnn = dn[nodeB];
      float v0, v1;
      if constexpr (AFF) {
        float wsn = wsum[nodeB];
        v0 = dnn * fmaf(af0, accB0, bf0 * wsn);
        v1 = dnn * fmaf(af1, accB1, bf1 * wsn);
        __half2 hv = __floats2half2_rn(v0, v1);
        Yout[((uint32_t)nodeB << 6) + lu] = *(const uint32_t*)&hv;
      } else {
        v0 = dnn * accB0;
        v1 = dnn * accB1;
        __half2 hv = __floats2half2_rn(v0 * dnn, v1 * dnn);
        Yout[((uint32_t)nodeB << 6) + lu] = *(const uint32_t*)&hv;
        if (l == 0) wsum[nodeB] = dsB;
      }
      s0 += v0; s1 += v1; q0 += v0 * v0; q1 += v1 * v1;
    }
  }

  // block epilogue: LDS cross-wave reduce, then 256 lane-atomics per block
  __shared__ float red[4][256];
  red[w][l] = s0; red[w][64 + l] = s1; red[w][128 + l] = q0; red[w][192 + l] = q1;
  __syncthreads();
  float t = red[0][tid] + red[1][tid] + red[2][tid] + red[3][tid];
  int comp = tid >> 6, li = tid & 63;
  int sh = blockIdx.x & (NSH - 1);
  float* dstp = ((comp & 2) ? sqS : sumS) + sh * DIMS;
  atomicAdd(&dstp[2 * li + (comp & 1)], t);
}

// ---------------- BN affine coefficients (reduces NSH shadow copies) ----------------
__global__ void affine_k(const float* __restrict__ sum, const float* __restrict__ sq,
                         const float* __restrict__ gamma, const float* __restrict__ beta,
                         float* __restrict__ a, float* __restrict__ b, float invn) {
  int d = threadIdx.x;
  float s = 0.f, q = 0.f;
  for (int k = 0; k < NSH; ++k) { s += sum[k * DIMS + d]; q += sq[k * DIMS + d]; }
  float mu = s * invn;
  float var = q * invn - mu * mu;
  float rs = rsqrtf(var + BN_EPS);
  float ad = rs * gamma[d];
  a[d] = ad;
  b[d] = beta[d] - mu * ad;
}

// fold pre-matmul affine into weights, TRANSPOSED fp16:
// Wt[o][d] = (half)(a2[d]*W[d][o]);  cp[o] = sum_d b2[d]*W[d][o] + cb[o]
__global__ void foldw_k(const float* __restrict__ W, const float* __restrict__ cb,
                        const float* __restrict__ a2, const float* __restrict__ b2,
                        __half* __restrict__ Wt, float* __restrict__ cp) {
  int o = blockIdx.x;
  int d = threadIdx.x;
  float w = W[d * DIMS + o];
  Wt[o * DIMS + d] = __float2half(a2[d] * w);
  __shared__ float red[128];
  red[d] = b2[d] * w;
  __syncthreads();
  for (int off = 64; off > 0; off >>= 1) {
    if (d < off) red[d] += red[d + off];
    __syncthreads();
  }
  if (d == 0) cp[o] = red[0] + cb[o];
}

// ---------------- Z = X @ W + cp via MFMA (fp16 in/out, f32 accum, fused BN stats) ----
__global__ __launch_bounds__(256) void matmul_k(
    const uint4* __restrict__ X, const uint4* __restrict__ Wt,
    const float* __restrict__ cp, __half* __restrict__ Z,
    float* __restrict__ sumS, float* __restrict__ sqS, int n) {
  int tid = threadIdx.x;
  int l = tid & 63, w = tid >> 6;
  int rowg = l & 15;  // A-row / B-col / D-col within tile
  int kg = l >> 4;    // k-group
  int r0 = (blockIdx.x * 4 + w) * 16;
  bool active = r0 < n;

  __shared__ float sred[4][128], qred[4][128];
  float svals[8], qvals[8];

  if (active) {
    f32x4 acc[8] = {};
    const uint4* xrow = X + (size_t)(r0 + rowg) * 16;
    bool arow_ok = (r0 + rowg) < n;
#pragma unroll
    for (int kk = 0; kk < 4; ++kk) {
      uint4 au = arow_ok ? xrow[kk * 4 + kg] : make_uint4(0u, 0u, 0u, 0u);
      f16x8 afr = as_f16x8(au);
#pragma unroll
      for (int c = 0; c < 8; ++c) {
        f16x8 bfr = as_f16x8(Wt[(size_t)(c * 16 + rowg) * 16 + kk * 4 + kg]);
        acc[c] = __builtin_amdgcn_mfma_f32_16x16x32_f16(afr, bfr, acc[c], 0, 0, 0);
      }
    }
#pragma unroll
    for (int c = 0; c < 8; ++c) {
      float cpv = cp[c * 16 + rowg];
      float s = 0.f, q = 0.f;
#pragma unroll
      for (int r = 0; r < 4; ++r) {
        int row = r0 + kg * 4 + r;
        float vv = acc[c][r] + cpv;
        bool ok = row < n;
        vv = ok ? vv : 0.f;
        s += vv; q += vv * vv;
        if (ok) Z[(size_t)row * DIMS + c * 16 + rowg] = __float2half(vv);
      }
      s += __shfl_xor(s, 16); s += __shfl_xor(s, 32);
      q += __shfl_xor(q, 16); q += __shfl_xor(q, 32);
      svals[c] = s; qvals[c] = q;
    }
  }
  if (active) {
    if (kg == 0) {
#pragma unroll
      for (int c = 0; c < 8; ++c) {
        sred[w][c * 16 + rowg] = svals[c];
        qred[w][c * 16 + rowg] = qvals[c];
      }
    }
  } else {
    sred[w][l] = 0.f; sred[w][64 + l] = 0.f;
    qred[w][l] = 0.f; qred[w][64 + l] = 0.f;
  }
  __syncthreads();
  int f = tid & 127;
  int sh = blockIdx.x & (NSH - 1);
  if (tid < 128) {
    float s = sred[0][f] + sred[1][f] + sred[2][f] + sred[3][f];
    atomicAdd(&sumS[sh * DIMS + f], s);
  } else {
    float q = qred[0][f] + qred[1][f] + qred[2][f] + qred[3][f];
    atomicAdd(&sqS[sh * DIMS + f], q);
  }
}

// ---------------- graph segment starts (node2graph is sorted) ----------------
__global__ void gstart_k(const int* __restrict__ n2g, int* __restrict__ gstart, int n, int G) {
  int i = blockIdx.x * blockDim.x + threadIdx.x;
  if (i >= n) return;
  int g = n2g[i];
  int gp = (i == 0) ? -1 : n2g[i - 1];
  for (int x = gp + 1; x <= g; ++x) gstart[x] = i;
  if (i == n - 1) {
    for (int x = g + 1; x <= G; ++x) gstart[x] = n;
  }
}

// ---------------- BN2-apply + relu + mean-pool + 128->2 projection ----------------
__global__ __launch_bounds__(512) void pool_pred_k(
    const uint4* __restrict__ Z, const int* __restrict__ gstart,
    const float* __restrict__ a3, const float* __restrict__ b3,
    const float* __restrict__ pw, const float* __restrict__ pb,
    float* __restrict__ out) {
  int g = blockIdx.x;
  int tid = threadIdx.x;
  int l = tid & 63, w = tid >> 6;  // w 0..7
  int grp = l >> 4, fl = l & 15;
  int f0 = fl * 8;
  float av[8], bv[8];
#pragma unroll
  for (int q = 0; q < 8; ++q) { av[q] = a3[f0 + q]; bv[q] = b3[f0 + q]; }
  int s = gstart[g], e = gstart[g + 1];
  float rs[8] = {0.f, 0.f, 0.f, 0.f, 0.f, 0.f, 0.f, 0.f};
  for (int ni = s + (w * 4 + grp); ni < e; ni += 32) {
    uint4 zv = Z[(size_t)ni * 16 + fl];
    const __half2* h = (const __half2*)&zv;
#pragma unroll
    for (int q = 0; q < 4; ++q) {
      float2 z = __half22float2(h[q]);
      rs[2 * q] += fmaxf(fmaf(z.x, av[2 * q], bv[2 * q]), 0.f);
      rs[2 * q + 1] += fmaxf(fmaf(z.y, av[2 * q + 1], bv[2 * q + 1]), 0.f);
    }
  }
  float p0 = 0.f, p1 = 0.f;
#pragma unroll
  for (int q = 0; q < 8; ++q) {
    p0 += rs[q] * pw[(f0 + q) * 2 + 0];
    p1 += rs[q] * pw[(f0 + q) * 2 + 1];
  }
  __shared__ float r[2][512];
  r[0][tid] = p0; r[1][tid] = p1;
  __syncthreads();
  for (int off = 256; off > 0; off >>= 1) {
    if (tid < off) { r[0][tid] += r[0][tid + off]; r[1][tid] += r[1][tid + off]; }
    __syncthreads();
  }
  if (tid == 0) {
    float inv = 1.f / fmaxf((float)(e - s), 1.f);
    out[g * 2 + 0] = r[0][0] * inv + pb[0];
    out[g * 2 + 1] = r[1][0] * inv + pb[1];
  }
}

// ---------------- host launch ----------------
extern "C" void kernel_launch(void* const* d_in, const int* in_sizes, int n_in,
                              void* d_out, int out_size, void* d_ws, size_t ws_size,
                              hipStream_t stream) {
  const float* nfeat  = (const float*)d_in[0];
  const int*   src    = (const int*)d_in[1];
  const int*   dst    = (const int*)d_in[2];
  const int*   n2g    = (const int*)d_in[3];
  // d_in[4] = num_graphs (device scalar) — derived from out_size instead
  const float* conv_w = (const float*)d_in[5];
  const float* conv_b = (const float*)d_in[6];
  const float* gamma1 = (const float*)d_in[7];
  const float* beta1  = (const float*)d_in[8];
  const float* gamma2 = (const float*)d_in[9];
  const float* beta2  = (const float*)d_in[10];
  const float* pred_w = (const float*)d_in[11];
  const float* pred_b = (const float*)d_in[12];
  float* out = (float*)d_out;
  (void)n_in; (void)ws_size;

  const int n = in_sizes[0] / DIMS;
  const int e = in_sizes[1];
  const int g = out_size / 2;
  const int nbins = (n + 511) >> 9;  // <= 512 (n <= 262144)

  char* p = (char*)d_ws;
  auto alloc = [&](size_t bytes) { char* r = p; p += (bytes + 255) & ~(size_t)255; return r; };
  uint32_t* Xp  = (uint32_t*)alloc((size_t)n * 64 * 4);  // dn-scaled input rows (fp16)
  uint32_t* W1  = (uint32_t*)alloc((size_t)n * 64 * 4);  // dn^2-scaled h1 rows (fp16)
  uint32_t* Y2  = (uint32_t*)alloc((size_t)n * 64 * 4);  // h2 rows (fp16)
  __half*   Zh  = (__half*)alloc((size_t)n * 64 * 4);    // matmul output rows (fp16)
  float* dnorm = (float*)alloc((size_t)n * 4);
  float* stat  = (float*)alloc(((size_t)6 * NSH * DIMS + n) * 4);  // stats + wsum
  float* wsum  = stat + 6 * NSH * DIMS;
  float* affA  = (float*)alloc(3 * DIMS * 4);
  float* affB  = (float*)alloc(3 * DIMS * 4);
  __half* Wt   = (__half*)alloc(DIMS * DIMS * 2);
  float* cp    = (float*)alloc(DIMS * 4);
  int* deg     = (int*)alloc((size_t)n * 4);
  int* row_off = (int*)alloc(((size_t)n + 1) * 4);
  int* adj     = (int*)alloc((size_t)e * 4);
  int* ebin    = (int*)alloc((size_t)e * 4);
  int* bcnt    = (int*)alloc(512 * 4);
  int* boff    = (int*)alloc(520 * 4);
  int* gcur    = (int*)alloc(512 * 4);
  int* bsum    = (int*)alloc(2048 * 4);
  int* gstart  = (int*)alloc(((size_t)g + 1) * 4);

  const int SLAB = NSH * DIMS;
  float* S0 = stat + 0 * SLAB; float* Q0 = stat + 1 * SLAB;
  float* S1 = stat + 2 * SLAB; float* Q1 = stat + 3 * SLAB;
  float* S2 = stat + 4 * SLAB; float* Q2 = stat + 5 * SLAB;

  const int nb = (n + 1023) / 1024;  // <= 256 required
  const float invn = 1.0f / (float)n;
  const int nwaves = GB * 4;

  // zero: bin counters (ints) + stats (floats)
  zero_k<<<dim3(((size_t)6 * SLAB + 255) / 256), dim3(256), 0, stream>>>(
      bcnt, (size_t)nbins, stat, (size_t)6 * SLAB);
  // binned CSR build
  bin_count_k<<<dim3(512), dim3(256), 0, stream>>>(dst, bcnt, e, nbins);
  bin_scan_k<<<dim3(1), dim3(512), 0, stream>>>(bcnt, nbins, boff, gcur, e);
  bin_scatter_k<<<dim3(1024), dim3(256), 0, stream>>>(src, dst, boff, gcur, ebin, e);
  deg_bins_k<<<dim3(nbins), dim3(256), 0, stream>>>(ebin, boff, deg, n);
  cvt_k<<<dim3(2048), dim3(256), 0, stream>>>(nfeat, Xp, deg, dnorm, (size_t)n * 64);
  scan1_k<<<dim3(nb), dim3(256), 0, stream>>>(deg, bsum, n);
  scan2_k<<<dim3(1), dim3(256), 0, stream>>>(bsum, nb, row_off, n, e);
  scan3_k<<<dim3(nb), dim3(256), 0, stream>>>(deg, bsum, row_off, n);
  adj_bins_k<<<dim3(nbins), dim3(256), 0, stream>>>(ebin, boff, row_off, adj, n);

  // hop 1: Xp -> W1 (stats of h1 -> S0/Q0; wsum written inline)
  gather_k<false><<<dim3(GB), dim3(256), 0, stream>>>(
      Xp, W1, row_off, adj, dnorm, wsum, nullptr, nullptr, S0, Q0, n, nwaves);
  affine_k<<<dim3(1), dim3(DIMS), 0, stream>>>(S0, Q0, gamma1, beta1, affA + 0, affB + 0, invn);
  // hop 2: W1 -> Y2 = h2 (stats -> S1/Q1)
  gather_k<true><<<dim3(GB), dim3(256), 0, stream>>>(
      W1, Y2, row_off, adj, dnorm, wsum, affA + 0, affB + 0, S1, Q1, n, nwaves);
  affine_k<<<dim3(1), dim3(DIMS), 0, stream>>>(S1, Q1, gamma1, beta1, affA + DIMS, affB + DIMS, invn);
  // fold stage-1 affine into transposed fp16 weights, then MFMA matmul (stats -> S2/Q2)
  foldw_k<<<dim3(DIMS), dim3(DIMS), 0, stream>>>(conv_w, conv_b, affA + DIMS, affB + DIMS, Wt, cp);
  matmul_k<<<dim3((n + 63) / 64), dim3(256), 0, stream>>>(
      (const uint4*)Y2, (const uint4*)Wt, cp, Zh, S2, Q2, n);
  affine_k<<<dim3(1), dim3(DIMS), 0, stream>>>(S2, Q2, gamma2, beta2, affA + 2 * DIMS, affB + 2 * DIMS, invn);
  // pooling + prediction
  gstart_k<<<dim3((n + 255) / 256), dim3(256), 0, stream>>>(n2g, gstart, n, g);
  pool_pred_k<<<dim3(g), dim3(512), 0, stream>>>((const uint4*)Zh, gstart,
                                                 affA + 2 * DIMS, affB + 2 * DIMS,
                                                 pred_w, pred_b, out);
}

// Round 8
// 486.865 us; speedup vs baseline: 1.7611x; 1.7611x over previous
//
#include <hip/hip_runtime.h>
#include <hip/hip_fp16.h>
#include <cstddef>
#include <cstdint>

constexpr int DIMS = 128;
constexpr float BN_EPS = 1e-5f;
constexpr int NSH = 64;   // stat shadow copies
constexpr int GB = 2048;  // gather grid blocks (x4 waves = 8192 waves)
constexpr int NPB = 512;  // partition blocks for CSR build

typedef _Float16 f16x8 __attribute__((ext_vector_type(8)));
typedef float f32x4 __attribute__((ext_vector_type(4)));

static __device__ __forceinline__ f16x8 as_f16x8(uint4 u) {
  union { uint4 u; f16x8 h; } x; x.u = u; return x.h;
}
static __device__ __forceinline__ __half2 as_h2(uint32_t u) {
  union { uint32_t u; __half2 h; } x; x.u = u; return x.h;
}

// ---------------- utility ----------------
__global__ void zero_k(float* __restrict__ fp, size_t nf) {
  size_t i = (size_t)blockIdx.x * blockDim.x + threadIdx.x;
  if (i < nf) fp[i] = 0.f;
}

// fp32 -> fp16 conversion with dn pre-scale (dn computed inline from deg):
// Xp[s] = dn[s] * nfeat[s];  also writes dnorm[s]
__global__ void cvt_k(const float* __restrict__ in, uint32_t* __restrict__ out,
                      const int* __restrict__ deg, float* __restrict__ dnorm, size_t n64) {
  size_t i = (size_t)blockIdx.x * blockDim.x + threadIdx.x;
  size_t stride = (size_t)gridDim.x * blockDim.x;
  const float2* in2 = (const float2*)in;
  for (; i < n64; i += stride) {
    size_t row = i >> 6;
    float d = rsqrtf(fmaxf((float)deg[row], 1.0f));
    if ((i & 63) == 0) dnorm[row] = d;
    float2 v = in2[i];
    __half2 h = __floats2half2_rn(v.x * d, v.y * d);
    out[i] = *(const uint32_t*)&h;
  }
}

// ---------------- two-pass binned CSR build (no global atomics) ----------------
// bins of 512 nodes; nbins <= 512 (n <= 262144)

// per-block histogram of its contiguous edge chunk -> C[block][bin]
__global__ __launch_bounds__(256) void cnt_k(const int* __restrict__ dst,
                                             int* __restrict__ C, int e, int chunk) {
  __shared__ int hist[512];
  int b = blockIdx.x;
  for (int j = threadIdx.x; j < 512; j += 256) hist[j] = 0;
  __syncthreads();
  int i0 = b * chunk;
  int i1 = i0 + chunk; if (i1 > e) i1 = e;
  for (int i = i0 + threadIdx.x; i < i1; i += 256)
    atomicAdd(&hist[dst[i] >> 9], 1);
  __syncthreads();
  for (int j = threadIdx.x; j < 512; j += 256) C[b * 512 + j] = hist[j];
}

// single block: per-bin totals -> exclusive bin scan (boff) -> rewrite C with
// per-(block,bin) starting offsets
__global__ __launch_bounds__(512) void pscan_k(int* __restrict__ C, int npb, int nbins,
                                               int* __restrict__ boff, int e) {
  int t = threadIdx.x;  // bin id
  int tot = 0;
  for (int b = 0; b < npb; ++b) tot += C[b * 512 + t];
  __shared__ int lds[512];
  lds[t] = tot; __syncthreads();
  for (int off = 1; off < 512; off <<= 1) {
    int add = (t >= off) ? lds[t - off] : 0;
    __syncthreads();
    lds[t] += add;
    __syncthreads();
  }
  int base = lds[t] - tot;  // exclusive prefix
  if (t < nbins) boff[t] = base;
  if (t == 0) boff[nbins] = e;
  int run = base;
  for (int b = 0; b < npb; ++b) {
    int c = C[b * 512 + t];
    C[b * 512 + t] = run;
    run += c;
  }
}

// scatter edges to bin-grouped ebin using LDS-only cursors
// ebin[p] = (src<<9) | (dst&511)   (src < 2^18 fits 27 bits)
__global__ __launch_bounds__(256) void scat_k(const int* __restrict__ src,
                                              const int* __restrict__ dst,
                                              const int* __restrict__ C,
                                              int* __restrict__ ebin, int e, int chunk) {
  __shared__ int cur[512];
  int b = blockIdx.x;
  for (int j = threadIdx.x; j < 512; j += 256) cur[j] = C[b * 512 + j];
  __syncthreads();
  int i0 = b * chunk;
  int i1 = i0 + chunk; if (i1 > e) i1 = e;
  for (int i = i0 + threadIdx.x; i < i1; i += 256) {
    int d = dst[i];
    int bin = d >> 9;
    int p = atomicAdd(&cur[bin], 1);
    ebin[p] = (src[i] << 9) | (d & 511);
  }
}

// per-node degree via LDS counters (no global atomics)
__global__ void deg_bins_k(const int* __restrict__ ebin, const int* __restrict__ boff,
                           int* __restrict__ deg, int n) {
  __shared__ int cnt[512];
  int b = blockIdx.x;
  for (int j = threadIdx.x; j < 512; j += 256) cnt[j] = 0;
  __syncthreads();
  int j0 = boff[b], j1 = boff[b + 1];
  for (int i = j0 + threadIdx.x; i < j1; i += 256) atomicAdd(&cnt[ebin[i] & 511], 1);
  __syncthreads();
  int base = b << 9;
  for (int j = threadIdx.x; j < 512; j += 256) {
    int node = base + j;
    if (node < n) deg[node] = cnt[j];
  }
}

// ---------------- CSR scan over degrees (row_off) ----------------
__global__ void scan1_k(const int* __restrict__ deg, int* __restrict__ bsum, int n) {
  __shared__ int lds[256];
  int t = threadIdx.x;
  int base = blockIdx.x * 1024;
  int s = 0;
  for (int i = t; i < 1024; i += 256) {
    int idx = base + i;
    s += (idx < n) ? deg[idx] : 0;
  }
  lds[t] = s; __syncthreads();
  for (int off = 128; off > 0; off >>= 1) {
    if (t < off) lds[t] += lds[t + off];
    __syncthreads();
  }
  if (t == 0) bsum[blockIdx.x] = lds[0];
}

__global__ void scan2_k(int* __restrict__ bsum, int nb, int* __restrict__ row_off, int n, int e) {
  __shared__ int lds[256];
  int t = threadIdx.x;
  int v = (t < nb) ? bsum[t] : 0;
  lds[t] = v; __syncthreads();
  for (int off = 1; off < 256; off <<= 1) {
    int add = (t >= off) ? lds[t - off] : 0;
    __syncthreads();
    lds[t] += add;
    __syncthreads();
  }
  if (t < nb) bsum[t] = lds[t] - v;  // exclusive base per chunk
  if (t == 0) row_off[n] = e;
}

__global__ void scan3_k(const int* __restrict__ deg, const int* __restrict__ bsum,
                        int* __restrict__ row_off, int n) {
  __shared__ int lds[256];
  int t = threadIdx.x;
  int base = blockIdx.x * 1024 + t * 4;
  int e0 = (base + 0 < n) ? deg[base + 0] : 0;
  int e1 = (base + 1 < n) ? deg[base + 1] : 0;
  int e2 = (base + 2 < n) ? deg[base + 2] : 0;
  int e3 = (base + 3 < n) ? deg[base + 3] : 0;
  int ts = e0 + e1 + e2 + e3;
  lds[t] = ts; __syncthreads();
  for (int off = 1; off < 256; off <<= 1) {
    int add = (t >= off) ? lds[t - off] : 0;
    __syncthreads();
    lds[t] += add;
    __syncthreads();
  }
  int ex = lds[t] - ts + bsum[blockIdx.x];
  if (base + 0 < n) row_off[base + 0] = ex;
  ex += e0;
  if (base + 1 < n) row_off[base + 1] = ex;
  ex += e1;
  if (base + 2 < n) row_off[base + 2] = ex;
  ex += e2;
  if (base + 3 < n) row_off[base + 3] = ex;
}

// adj placement: all writes fall in the bin's contiguous adj region (L2-hot)
__global__ void adj_bins_k(const int* __restrict__ ebin, const int* __restrict__ boff,
                           const int* __restrict__ row_off, int* __restrict__ adj, int n) {
  __shared__ int cur[512];
  __shared__ int ro[512];
  int b = blockIdx.x;
  int base = b << 9;
  for (int j = threadIdx.x; j < 512; j += 256) {
    cur[j] = 0;
    int node = base + j;
    ro[j] = (node < n) ? row_off[node] : 0;
  }
  __syncthreads();
  int j0 = boff[b], j1 = boff[b + 1];
  for (int i = j0 + threadIdx.x; i < j1; i += 256) {
    int pk = ebin[i];
    int dl = pk & 511;
    int s = pk >> 9;
    int p = atomicAdd(&cur[dl], 1);
    adj[ro[dl] + p] = s;
  }
}

// ---------------- propagation hop: grid-stride, TWO nodes per wave in flight -------
// Lane owns 2 features (half2 row element). 8-deep edge pipeline per node stream.
// AFF=false (hop1): acc = sum Xp[s]; v = dn*acc (stats); store W1 = dn^2*acc;
//                   also wsum[node] = sum dn[s] (computed inline, lane 0 writes).
// AFF=true  (hop2): acc = sum W1[s]; v = dn*(a*acc + b*wsum[n]) (stats); store v.
template <bool AFF>
__global__ __launch_bounds__(256) void gather_k(
    const uint32_t* __restrict__ Xu, uint32_t* __restrict__ Yout,
    const int* __restrict__ row_off, const int* __restrict__ adj,
    const float* __restrict__ dn, float* __restrict__ wsum,
    const float* __restrict__ a, const float* __restrict__ b,
    float* __restrict__ sumS, float* __restrict__ sqS, int n, int nwaves) {
  int tid = threadIdx.x;
  int l = tid & 63, w = tid >> 6;
  int wid = blockIdx.x * 4 + w;  // wave-uniform
  uint32_t lu = (uint32_t)l;
  int f0 = 2 * l;
  float af0 = 1.f, bf0 = 0.f, af1 = 1.f, bf1 = 0.f;
  if (AFF) { af0 = a[f0]; bf0 = b[f0]; af1 = a[f0 + 1]; bf1 = b[f0 + 1]; }
  float s0 = 0.f, s1 = 0.f, q0 = 0.f, q1 = 0.f;

  for (int nodeA = wid; nodeA < n; nodeA += 2 * nwaves) {
    const int nodeB = nodeA + nwaves;
    const bool hasB = nodeB < n;
    int ja = row_off[nodeA];
    const int ea = row_off[nodeA + 1];
    int jb = hasB ? row_off[nodeB] : 0;
    const int eb = hasB ? row_off[nodeB + 1] : 0;
    float accA0 = 0.f, accA1 = 0.f, accB0 = 0.f, accB1 = 0.f;
    float dsA = 0.f, dsB = 0.f;

    while ((ja < ea) || (jb < eb)) {
      uint32_t xa[8], xb[8];
      float da[8], db[8];
      const bool runA = ja < ea, runB = jb < eb;
      if (runA) {  // issue 8 loads for stream A
#pragma unroll
        for (int t = 0; t < 8; ++t) {
          int jj = ja + t;
          int jc = jj < ea ? jj : ea - 1;
          uint32_t sj = (uint32_t)adj[jc];
          uint32_t v = Xu[(sj << 6) + lu];
          xa[t] = (jj < ea) ? v : 0u;
          if constexpr (!AFF) {
            float dv = dn[sj];
            da[t] = (jj < ea) ? dv : 0.f;
          }
        }
      }
      if (runB) {  // issue 8 more (independent -> 16 in flight)
#pragma unroll
        for (int t = 0; t < 8; ++t) {
          int jj = jb + t;
          int jc = jj < eb ? jj : eb - 1;
          uint32_t sj = (uint32_t)adj[jc];
          uint32_t v = Xu[(sj << 6) + lu];
          xb[t] = (jj < eb) ? v : 0u;
          if constexpr (!AFF) {
            float dv = dn[sj];
            db[t] = (jj < eb) ? dv : 0.f;
          }
        }
      }
      if (runA) {  // depth-2 fp16 pairwise tree, fp32 accumulate
        __half2 t0 = __hadd2(as_h2(xa[0]), as_h2(xa[1]));
        __half2 t1 = __hadd2(as_h2(xa[2]), as_h2(xa[3]));
        __half2 t2 = __hadd2(as_h2(xa[4]), as_h2(xa[5]));
        __half2 t3 = __hadd2(as_h2(xa[6]), as_h2(xa[7]));
        float2 u0 = __half22float2(__hadd2(t0, t1));
        float2 u1 = __half22float2(__hadd2(t2, t3));
        accA0 += u0.x + u1.x;
        accA1 += u0.y + u1.y;
        if constexpr (!AFF)
          dsA += ((da[0] + da[1]) + (da[2] + da[3])) + ((da[4] + da[5]) + (da[6] + da[7]));
        ja += 8;
      }
      if (runB) {
        __half2 t0 = __hadd2(as_h2(xb[0]), as_h2(xb[1]));
        __half2 t1 = __hadd2(as_h2(xb[2]), as_h2(xb[3]));
        __half2 t2 = __hadd2(as_h2(xb[4]), as_h2(xb[5]));
        __half2 t3 = __hadd2(as_h2(xb[6]), as_h2(xb[7]));
        float2 u0 = __half22float2(__hadd2(t0, t1));
        float2 u1 = __half22float2(__hadd2(t2, t3));
        accB0 += u0.x + u1.x;
        accB1 += u0.y + u1.y;
        if constexpr (!AFF)
          dsB += ((db[0] + db[1]) + (db[2] + db[3])) + ((db[4] + db[5]) + (db[6] + db[7]));
        jb += 8;
      }
    }

    {  // finalize node A
      float dnn = dn[nodeA];
      float v0, v1;
      if constexpr (AFF) {
        float wsn = wsum[nodeA];
        v0 = dnn * fmaf(af0, accA0, bf0 * wsn);
        v1 = dnn * fmaf(af1, accA1, bf1 * wsn);
        __half2 hv = __floats2half2_rn(v0, v1);
        Yout[((uint32_t)nodeA << 6) + lu] = *(const uint32_t*)&hv;
      } else {
        v0 = dnn * accA0;
        v1 = dnn * accA1;
        __half2 hv = __floats2half2_rn(v0 * dnn, v1 * dnn);  // W1 = dn^2*acc
        Yout[((uint32_t)nodeA << 6) + lu] = *(const uint32_t*)&hv;
        if (l == 0) wsum[nodeA] = dsA;
      }
      s0 += v0; s1 += v1; q0 += v0 * v0; q1 += v1 * v1;
    }
    if (hasB) {  // finalize node B
      float dnn = dn[nodeB];
      float v0, v1;
      if constexpr (AFF) {
        float wsn = wsum[nodeB];
        v0 = dnn * fmaf(af0, accB0, bf0 * wsn);
        v1 = dnn * fmaf(af1, accB1, bf1 * wsn);
        __half2 hv = __floats2half2_rn(v0, v1);
        Yout[((uint32_t)nodeB << 6) + lu] = *(const uint32_t*)&hv;
      } else {
        v0 = dnn * accB0;
        v1 = dnn * accB1;
        __half2 hv = __floats2half2_rn(v0 * dnn, v1 * dnn);
        Yout[((uint32_t)nodeB << 6) + lu] = *(const uint32_t*)&hv;
        if (l == 0) wsum[nodeB] = dsB;
      }
      s0 += v0; s1 += v1; q0 += v0 * v0; q1 += v1 * v1;
    }
  }

  // block epilogue: LDS cross-wave reduce, then 256 lane-atomics per block
  __shared__ float red[4][256];
  red[w][l] = s0; red[w][64 + l] = s1; red[w][128 + l] = q0; red[w][192 + l] = q1;
  __syncthreads();
  float t = red[0][tid] + red[1][tid] + red[2][tid] + red[3][tid];
  int comp = tid >> 6, li = tid & 63;
  int sh = blockIdx.x & (NSH - 1);
  float* dstp = ((comp & 2) ? sqS : sumS) + sh * DIMS;
  atomicAdd(&dstp[2 * li + (comp & 1)], t);
}

// ---------------- BN affine coefficients (reduces NSH shadow copies) ----------------
__global__ void affine_k(const float* __restrict__ sum, const float* __restrict__ sq,
                         const float* __restrict__ gamma, const float* __restrict__ beta,
                         float* __restrict__ a, float* __restrict__ b, float invn) {
  int d = threadIdx.x;
  float s = 0.f, q = 0.f;
  for (int k = 0; k < NSH; ++k) { s += sum[k * DIMS + d]; q += sq[k * DIMS + d]; }
  float mu = s * invn;
  float var = q * invn - mu * mu;
  float rs = rsqrtf(var + BN_EPS);
  float ad = rs * gamma[d];
  a[d] = ad;
  b[d] = beta[d] - mu * ad;
}

// fold pre-matmul affine into weights, TRANSPOSED fp16:
// Wt[o][d] = (half)(a2[d]*W[d][o]);  cp[o] = sum_d b2[d]*W[d][o] + cb[o]
__global__ void foldw_k(const float* __restrict__ W, const float* __restrict__ cb,
                        const float* __restrict__ a2, const float* __restrict__ b2,
                        __half* __restrict__ Wt, float* __restrict__ cp) {
  int o = blockIdx.x;
  int d = threadIdx.x;
  float w = W[d * DIMS + o];
  Wt[o * DIMS + d] = __float2half(a2[d] * w);
  __shared__ float red[128];
  red[d] = b2[d] * w;
  __syncthreads();
  for (int off = 64; off > 0; off >>= 1) {
    if (d < off) red[d] += red[d + off];
    __syncthreads();
  }
  if (d == 0) cp[o] = red[0] + cb[o];
}

// ---------------- Z = X @ W + cp via MFMA (fp16 in/out, f32 accum, fused BN stats) ----
__global__ __launch_bounds__(256) void matmul_k(
    const uint4* __restrict__ X, const uint4* __restrict__ Wt,
    const float* __restrict__ cp, __half* __restrict__ Z,
    float* __restrict__ sumS, float* __restrict__ sqS, int n) {
  int tid = threadIdx.x;
  int l = tid & 63, w = tid >> 6;
  int rowg = l & 15;  // A-row / B-col / D-col within tile
  int kg = l >> 4;    // k-group
  int r0 = (blockIdx.x * 4 + w) * 16;
  bool active = r0 < n;

  __shared__ float sred[4][128], qred[4][128];
  float svals[8], qvals[8];

  if (active) {
    f32x4 acc[8] = {};
    const uint4* xrow = X + (size_t)(r0 + rowg) * 16;
    bool arow_ok = (r0 + rowg) < n;
#pragma unroll
    for (int kk = 0; kk < 4; ++kk) {
      uint4 au = arow_ok ? xrow[kk * 4 + kg] : make_uint4(0u, 0u, 0u, 0u);
      f16x8 afr = as_f16x8(au);
#pragma unroll
      for (int c = 0; c < 8; ++c) {
        f16x8 bfr = as_f16x8(Wt[(size_t)(c * 16 + rowg) * 16 + kk * 4 + kg]);
        acc[c] = __builtin_amdgcn_mfma_f32_16x16x32_f16(afr, bfr, acc[c], 0, 0, 0);
      }
    }
#pragma unroll
    for (int c = 0; c < 8; ++c) {
      float cpv = cp[c * 16 + rowg];
      float s = 0.f, q = 0.f;
#pragma unroll
      for (int r = 0; r < 4; ++r) {
        int row = r0 + kg * 4 + r;
        float vv = acc[c][r] + cpv;
        bool ok = row < n;
        vv = ok ? vv : 0.f;
        s += vv; q += vv * vv;
        if (ok) Z[(size_t)row * DIMS + c * 16 + rowg] = __float2half(vv);
      }
      s += __shfl_xor(s, 16); s += __shfl_xor(s, 32);
      q += __shfl_xor(q, 16); q += __shfl_xor(q, 32);
      svals[c] = s; qvals[c] = q;
    }
  }
  if (active) {
    if (kg == 0) {
#pragma unroll
      for (int c = 0; c < 8; ++c) {
        sred[w][c * 16 + rowg] = svals[c];
        qred[w][c * 16 + rowg] = qvals[c];
      }
    }
  } else {
    sred[w][l] = 0.f; sred[w][64 + l] = 0.f;
    qred[w][l] = 0.f; qred[w][64 + l] = 0.f;
  }
  __syncthreads();
  int f = tid & 127;
  int sh = blockIdx.x & (NSH - 1);
  if (tid < 128) {
    float s = sred[0][f] + sred[1][f] + sred[2][f] + sred[3][f];
    atomicAdd(&sumS[sh * DIMS + f], s);
  } else {
    float q = qred[0][f] + qred[1][f] + qred[2][f] + qred[3][f];
    atomicAdd(&sqS[sh * DIMS + f], q);
  }
}

// ---------------- graph segment starts (node2graph is sorted) ----------------
__global__ void gstart_k(const int* __restrict__ n2g, int* __restrict__ gstart, int n, int G) {
  int i = blockIdx.x * blockDim.x + threadIdx.x;
  if (i >= n) return;
  int g = n2g[i];
  int gp = (i == 0) ? -1 : n2g[i - 1];
  for (int x = gp + 1; x <= g; ++x) gstart[x] = i;
  if (i == n - 1) {
    for (int x = g + 1; x <= G; ++x) gstart[x] = n;
  }
}

// ---------------- BN2-apply + relu + mean-pool + 128->2 projection ----------------
__global__ __launch_bounds__(512) void pool_pred_k(
    const uint4* __restrict__ Z, const int* __restrict__ gstart,
    const float* __restrict__ a3, const float* __restrict__ b3,
    const float* __restrict__ pw, const float* __restrict__ pb,
    float* __restrict__ out) {
  int g = blockIdx.x;
  int tid = threadIdx.x;
  int l = tid & 63, w = tid >> 6;  // w 0..7
  int grp = l >> 4, fl = l & 15;
  int f0 = fl * 8;
  float av[8], bv[8];
#pragma unroll
  for (int q = 0; q < 8; ++q) { av[q] = a3[f0 + q]; bv[q] = b3[f0 + q]; }
  int s = gstart[g], e = gstart[g + 1];
  float rs[8] = {0.f, 0.f, 0.f, 0.f, 0.f, 0.f, 0.f, 0.f};
  for (int ni = s + (w * 4 + grp); ni < e; ni += 32) {
    uint4 zv = Z[(size_t)ni * 16 + fl];
    const __half2* h = (const __half2*)&zv;
#pragma unroll
    for (int q = 0; q < 4; ++q) {
      float2 z = __half22float2(h[q]);
      rs[2 * q] += fmaxf(fmaf(z.x, av[2 * q], bv[2 * q]), 0.f);
      rs[2 * q + 1] += fmaxf(fmaf(z.y, av[2 * q + 1], bv[2 * q + 1]), 0.f);
    }
  }
  float p0 = 0.f, p1 = 0.f;
#pragma unroll
  for (int q = 0; q < 8; ++q) {
    p0 += rs[q] * pw[(f0 + q) * 2 + 0];
    p1 += rs[q] * pw[(f0 + q) * 2 + 1];
  }
  __shared__ float r[2][512];
  r[0][tid] = p0; r[1][tid] = p1;
  __syncthreads();
  for (int off = 256; off > 0; off >>= 1) {
    if (tid < off) { r[0][tid] += r[0][tid + off]; r[1][tid] += r[1][tid + off]; }
    __syncthreads();
  }
  if (tid == 0) {
    float inv = 1.f / fmaxf((float)(e - s), 1.f);
    out[g * 2 + 0] = r[0][0] * inv + pb[0];
    out[g * 2 + 1] = r[1][0] * inv + pb[1];
  }
}

// ---------------- host launch ----------------
extern "C" void kernel_launch(void* const* d_in, const int* in_sizes, int n_in,
                              void* d_out, int out_size, void* d_ws, size_t ws_size,
                              hipStream_t stream) {
  const float* nfeat  = (const float*)d_in[0];
  const int*   src    = (const int*)d_in[1];
  const int*   dst    = (const int*)d_in[2];
  const int*   n2g    = (const int*)d_in[3];
  // d_in[4] = num_graphs (device scalar) — derived from out_size instead
  const float* conv_w = (const float*)d_in[5];
  const float* conv_b = (const float*)d_in[6];
  const float* gamma1 = (const float*)d_in[7];
  const float* beta1  = (const float*)d_in[8];
  const float* gamma2 = (const float*)d_in[9];
  const float* beta2  = (const float*)d_in[10];
  const float* pred_w = (const float*)d_in[11];
  const float* pred_b = (const float*)d_in[12];
  float* out = (float*)d_out;
  (void)n_in; (void)ws_size;

  const int n = in_sizes[0] / DIMS;
  const int e = in_sizes[1];
  const int g = out_size / 2;
  const int nbins = (n + 511) >> 9;  // <= 512 (n <= 262144)

  char* p = (char*)d_ws;
  auto alloc = [&](size_t bytes) { char* r = p; p += (bytes + 255) & ~(size_t)255; return r; };
  uint32_t* Xp  = (uint32_t*)alloc((size_t)n * 64 * 4);  // dn-scaled input rows (fp16)
  uint32_t* W1  = (uint32_t*)alloc((size_t)n * 64 * 4);  // dn^2-scaled h1 rows (fp16)
  uint32_t* Y2  = (uint32_t*)alloc((size_t)n * 64 * 4);  // h2 rows (fp16)
  __half*   Zh  = (__half*)alloc((size_t)n * 64 * 4);    // matmul output rows (fp16)
  float* dnorm = (float*)alloc((size_t)n * 4);
  float* stat  = (float*)alloc(((size_t)6 * NSH * DIMS + n) * 4);  // stats + wsum
  float* wsum  = stat + 6 * NSH * DIMS;
  float* affA  = (float*)alloc(3 * DIMS * 4);
  float* affB  = (float*)alloc(3 * DIMS * 4);
  __half* Wt   = (__half*)alloc(DIMS * DIMS * 2);
  float* cp    = (float*)alloc(DIMS * 4);
  int* deg     = (int*)alloc((size_t)n * 4);
  int* row_off = (int*)alloc(((size_t)n + 1) * 4);
  int* adj     = (int*)alloc((size_t)e * 4);
  int* ebin    = (int*)alloc((size_t)e * 4);
  int* Cmat    = (int*)alloc((size_t)NPB * 512 * 4);
  int* boff    = (int*)alloc(520 * 4);
  int* bsum    = (int*)alloc(2048 * 4);
  int* gstart  = (int*)alloc(((size_t)g + 1) * 4);

  const int SLAB = NSH * DIMS;
  float* S0 = stat + 0 * SLAB; float* Q0 = stat + 1 * SLAB;
  float* S1 = stat + 2 * SLAB; float* Q1 = stat + 3 * SLAB;
  float* S2 = stat + 4 * SLAB; float* Q2 = stat + 5 * SLAB;

  const int nb = (n + 1023) / 1024;  // <= 256 required
  const float invn = 1.0f / (float)n;
  const int nwaves = GB * 4;
  const int chunk = (e + NPB - 1) / NPB;

  // zero stats
  zero_k<<<dim3(((size_t)6 * SLAB + 255) / 256), dim3(256), 0, stream>>>(stat, (size_t)6 * SLAB);
  // two-pass binned CSR build (no global atomics)
  cnt_k<<<dim3(NPB), dim3(256), 0, stream>>>(dst, Cmat, e, chunk);
  pscan_k<<<dim3(1), dim3(512), 0, stream>>>(Cmat, NPB, nbins, boff, e);
  scat_k<<<dim3(NPB), dim3(256), 0, stream>>>(src, dst, Cmat, ebin, e, chunk);
  deg_bins_k<<<dim3(nbins), dim3(256), 0, stream>>>(ebin, boff, deg, n);
  cvt_k<<<dim3(2048), dim3(256), 0, stream>>>(nfeat, Xp, deg, dnorm, (size_t)n * 64);
  scan1_k<<<dim3(nb), dim3(256), 0, stream>>>(deg, bsum, n);
  scan2_k<<<dim3(1), dim3(256), 0, stream>>>(bsum, nb, row_off, n, e);
  scan3_k<<<dim3(nb), dim3(256), 0, stream>>>(deg, bsum, row_off, n);
  adj_bins_k<<<dim3(nbins), dim3(256), 0, stream>>>(ebin, boff, row_off, adj, n);

  // hop 1: Xp -> W1 (stats of h1 -> S0/Q0; wsum written inline)
  gather_k<false><<<dim3(GB), dim3(256), 0, stream>>>(
      Xp, W1, row_off, adj, dnorm, wsum, nullptr, nullptr, S0, Q0, n, nwaves);
  affine_k<<<dim3(1), dim3(DIMS), 0, stream>>>(S0, Q0, gamma1, beta1, affA + 0, affB + 0, invn);
  // hop 2: W1 -> Y2 = h2 (stats -> S1/Q1)
  gather_k<true><<<dim3(GB), dim3(256), 0, stream>>>(
      W1, Y2, row_off, adj, dnorm, wsum, affA + 0, affB + 0, S1, Q1, n, nwaves);
  affine_k<<<dim3(1), dim3(DIMS), 0, stream>>>(S1, Q1, gamma1, beta1, affA + DIMS, affB + DIMS, invn);
  // fold stage-1 affine into transposed fp16 weights, then MFMA matmul (stats -> S2/Q2)
  foldw_k<<<dim3(DIMS), dim3(DIMS), 0, stream>>>(conv_w, conv_b, affA + DIMS, affB + DIMS, Wt, cp);
  matmul_k<<<dim3((n + 63) / 64), dim3(256), 0, stream>>>(
      (const uint4*)Y2, (const uint4*)Wt, cp, Zh, S2, Q2, n);
  affine_k<<<dim3(1), dim3(DIMS), 0, stream>>>(S2, Q2, gamma2, beta2, affA + 2 * DIMS, affB + 2 * DIMS, invn);
  // pooling + prediction
  gstart_k<<<dim3((n + 255) / 256), dim3(256), 0, stream>>>(n2g, gstart, n, g);
  pool_pred_k<<<dim3(g), dim3(512), 0, stream>>>((const uint4*)Zh, gstart,
                                                 affA + 2 * DIMS, affB + 2 * DIMS,
                                                 pred_w, pred_b, out);
}

// Round 9
// 285.081 us; speedup vs baseline: 3.0076x; 1.7078x over previous
//
#include <hip/hip_runtime.h>
#include <hip/hip_fp16.h>
#include <cstddef>
#include <cstdint>

constexpr int DIMS = 128;
constexpr float BN_EPS = 1e-5f;
constexpr int NSH = 64;   // stat shadow copies
constexpr int GB = 2048;  // gather grid blocks (x4 waves = 8192 waves)
constexpr int NPB = 512;  // partition blocks for CSR build

typedef _Float16 f16x8 __attribute__((ext_vector_type(8)));
typedef float f32x4 __attribute__((ext_vector_type(4)));

static __device__ __forceinline__ f16x8 as_f16x8(uint4 u) {
  union { uint4 u; f16x8 h; } x; x.u = u; return x.h;
}
static __device__ __forceinline__ __half2 as_h2(uint32_t u) {
  union { uint32_t u; __half2 h; } x; x.u = u; return x.h;
}

// ---------------- utility ----------------
__global__ void zero_k(float* __restrict__ fp, size_t nf) {
  size_t i = (size_t)blockIdx.x * blockDim.x + threadIdx.x;
  if (i < nf) fp[i] = 0.f;
}

// fp32 -> fp16 conversion with dn pre-scale (dn computed inline from deg):
// Xp[s] = dn[s] * nfeat[s];  also writes dnorm[s]
__global__ void cvt_k(const float* __restrict__ in, uint32_t* __restrict__ out,
                      const int* __restrict__ deg, float* __restrict__ dnorm, size_t n64) {
  size_t i = (size_t)blockIdx.x * blockDim.x + threadIdx.x;
  size_t stride = (size_t)gridDim.x * blockDim.x;
  const float2* in2 = (const float2*)in;
  for (; i < n64; i += stride) {
    size_t row = i >> 6;
    float d = rsqrtf(fmaxf((float)deg[row], 1.0f));
    if ((i & 63) == 0) dnorm[row] = d;
    float2 v = in2[i];
    __half2 h = __floats2half2_rn(v.x * d, v.y * d);
    out[i] = *(const uint32_t*)&h;
  }
}

// ---------------- two-pass binned CSR build (no global atomics) ----------------
// bins of 512 nodes; nbins <= 512 (n <= 262144). C layout: C[block*512 + bin].

// per-block histogram of its contiguous edge chunk -> C[block][bin]
__global__ __launch_bounds__(256) void cnt_k(const int* __restrict__ dst,
                                             int* __restrict__ C, int e, int chunk) {
  __shared__ int hist[512];
  int b = blockIdx.x;
  for (int j = threadIdx.x; j < 512; j += 256) hist[j] = 0;
  __syncthreads();
  int i0 = b * chunk;
  int i1 = i0 + chunk; if (i1 > e) i1 = e;
  for (int i = i0 + threadIdx.x; i < i1; i += 256)
    atomicAdd(&hist[dst[i] >> 9], 1);
  __syncthreads();
  for (int j = threadIdx.x; j < 512; j += 256) C[b * 512 + j] = hist[j];
}

// one block PER BIN: exclusive scan down the bin's column of C; emits per-bin total
__global__ __launch_bounds__(512) void colscan_k(int* __restrict__ C, int* __restrict__ tot) {
  int j = blockIdx.x;   // bin
  int t = threadIdx.x;  // partition block
  int v = C[t * 512 + j];
  __shared__ int lds[512];
  lds[t] = v; __syncthreads();
  for (int off = 1; off < 512; off <<= 1) {
    int add = (t >= off) ? lds[t - off] : 0;
    __syncthreads();
    lds[t] += add;
    __syncthreads();
  }
  C[t * 512 + j] = lds[t] - v;  // exclusive within-column prefix
  if (t == 511) tot[j] = lds[511];
}

// single small block: exclusive scan of per-bin totals -> boff
__global__ __launch_bounds__(512) void bscan_k(const int* __restrict__ tot, int nbins,
                                               int* __restrict__ boff, int e) {
  int t = threadIdx.x;
  int v = tot[t];
  __shared__ int lds[512];
  lds[t] = v; __syncthreads();
  for (int off = 1; off < 512; off <<= 1) {
    int add = (t >= off) ? lds[t - off] : 0;
    __syncthreads();
    lds[t] += add;
    __syncthreads();
  }
  boff[t] = lds[t] - v;
  if (t == 0) boff[nbins] = e;
}

// scatter edges to bin-grouped ebin using LDS-only cursors
// ebin[p] = (src<<9) | (dst&511)   (src < 2^18 fits 27 bits)
__global__ __launch_bounds__(256) void scat_k(const int* __restrict__ src,
                                              const int* __restrict__ dst,
                                              const int* __restrict__ C,
                                              const int* __restrict__ boff,
                                              int* __restrict__ ebin, int e, int chunk) {
  __shared__ int cur[512];
  int b = blockIdx.x;
  for (int j = threadIdx.x; j < 512; j += 256) cur[j] = boff[j] + C[b * 512 + j];
  __syncthreads();
  int i0 = b * chunk;
  int i1 = i0 + chunk; if (i1 > e) i1 = e;
  for (int i = i0 + threadIdx.x; i < i1; i += 256) {
    int d = dst[i];
    int bin = d >> 9;
    int p = atomicAdd(&cur[bin], 1);
    ebin[p] = (src[i] << 9) | (d & 511);
  }
}

// per-node degree via LDS counters (no global atomics)
__global__ void deg_bins_k(const int* __restrict__ ebin, const int* __restrict__ boff,
                           int* __restrict__ deg, int n) {
  __shared__ int cnt[512];
  int b = blockIdx.x;
  for (int j = threadIdx.x; j < 512; j += 256) cnt[j] = 0;
  __syncthreads();
  int j0 = boff[b], j1 = boff[b + 1];
  for (int i = j0 + threadIdx.x; i < j1; i += 256) atomicAdd(&cnt[ebin[i] & 511], 1);
  __syncthreads();
  int base = b << 9;
  for (int j = threadIdx.x; j < 512; j += 256) {
    int node = base + j;
    if (node < n) deg[node] = cnt[j];
  }
}

// ---------------- CSR scan over degrees (row_off) ----------------
__global__ void scan1_k(const int* __restrict__ deg, int* __restrict__ bsum, int n) {
  __shared__ int lds[256];
  int t = threadIdx.x;
  int base = blockIdx.x * 1024;
  int s = 0;
  for (int i = t; i < 1024; i += 256) {
    int idx = base + i;
    s += (idx < n) ? deg[idx] : 0;
  }
  lds[t] = s; __syncthreads();
  for (int off = 128; off > 0; off >>= 1) {
    if (t < off) lds[t] += lds[t + off];
    __syncthreads();
  }
  if (t == 0) bsum[blockIdx.x] = lds[0];
}

__global__ void scan2_k(int* __restrict__ bsum, int nb, int* __restrict__ row_off, int n, int e) {
  __shared__ int lds[256];
  int t = threadIdx.x;
  int v = (t < nb) ? bsum[t] : 0;
  lds[t] = v; __syncthreads();
  for (int off = 1; off < 256; off <<= 1) {
    int add = (t >= off) ? lds[t - off] : 0;
    __syncthreads();
    lds[t] += add;
    __syncthreads();
  }
  if (t < nb) bsum[t] = lds[t] - v;  // exclusive base per chunk
  if (t == 0) row_off[n] = e;
}

__global__ void scan3_k(const int* __restrict__ deg, const int* __restrict__ bsum,
                        int* __restrict__ row_off, int n) {
  __shared__ int lds[256];
  int t = threadIdx.x;
  int base = blockIdx.x * 1024 + t * 4;
  int e0 = (base + 0 < n) ? deg[base + 0] : 0;
  int e1 = (base + 1 < n) ? deg[base + 1] : 0;
  int e2 = (base + 2 < n) ? deg[base + 2] : 0;
  int e3 = (base + 3 < n) ? deg[base + 3] : 0;
  int ts = e0 + e1 + e2 + e3;
  lds[t] = ts; __syncthreads();
  for (int off = 1; off < 256; off <<= 1) {
    int add = (t >= off) ? lds[t - off] : 0;
    __syncthreads();
    lds[t] += add;
    __syncthreads();
  }
  int ex = lds[t] - ts + bsum[blockIdx.x];
  if (base + 0 < n) row_off[base + 0] = ex;
  ex += e0;
  if (base + 1 < n) row_off[base + 1] = ex;
  ex += e1;
  if (base + 2 < n) row_off[base + 2] = ex;
  ex += e2;
  if (base + 3 < n) row_off[base + 3] = ex;
}

// adj placement (bin-local, L2-hot) + wsum[node] = sum dn[src] via LDS accumulators
__global__ __launch_bounds__(512) void adj_bins_k(
    const int* __restrict__ ebin, const int* __restrict__ boff,
    const int* __restrict__ row_off, const float* __restrict__ dnorm,
    int* __restrict__ adj, float* __restrict__ wsum, int n) {
  __shared__ int cur[512];
  __shared__ int ro[512];
  __shared__ float ws[512];
  int b = blockIdx.x;
  int base = b << 9;
  for (int j = threadIdx.x; j < 512; j += 512) {
    cur[j] = 0;
    ws[j] = 0.f;
    int node = base + j;
    ro[j] = (node < n) ? row_off[node] : 0;
  }
  __syncthreads();
  int j0 = boff[b], j1 = boff[b + 1];
  for (int i = j0 + threadIdx.x; i < j1; i += 512) {
    int pk = ebin[i];
    int dl = pk & 511;
    int s = pk >> 9;
    int p = atomicAdd(&cur[dl], 1);
    adj[ro[dl] + p] = s;
    atomicAdd(&ws[dl], dnorm[s]);
  }
  __syncthreads();
  for (int j = threadIdx.x; j < 512; j += 512) {
    int node = base + j;
    if (node < n) wsum[node] = ws[j];
  }
}

// ---------------- propagation hop: grid-stride, TWO nodes per wave in flight -------
// Lane owns 2 features (half2 row element). 8-deep edge pipeline per node stream.
// AFF=false (hop1): acc = sum Xp[s]; v = dn*acc (stats); store W1 = dn*v = dn^2*acc.
// AFF=true  (hop2): acc = sum W1[s]; v = dn*(a*acc + b*wsum[n]) (stats); store v.
template <bool AFF>
__global__ __launch_bounds__(256) void gather_k(
    const uint32_t* __restrict__ Xu, uint32_t* __restrict__ Yout,
    const int* __restrict__ row_off, const int* __restrict__ adj,
    const float* __restrict__ dn, const float* __restrict__ wsum,
    const float* __restrict__ a, const float* __restrict__ b,
    float* __restrict__ sumS, float* __restrict__ sqS, int n, int nwaves) {
  int tid = threadIdx.x;
  int l = tid & 63, w = tid >> 6;
  int wid = blockIdx.x * 4 + w;  // wave-uniform
  uint32_t lu = (uint32_t)l;
  int f0 = 2 * l;
  float af0 = 1.f, bf0 = 0.f, af1 = 1.f, bf1 = 0.f;
  if (AFF) { af0 = a[f0]; bf0 = b[f0]; af1 = a[f0 + 1]; bf1 = b[f0 + 1]; }
  float s0 = 0.f, s1 = 0.f, q0 = 0.f, q1 = 0.f;

  for (int nodeA = wid; nodeA < n; nodeA += 2 * nwaves) {
    const int nodeB = nodeA + nwaves;
    const bool hasB = nodeB < n;
    int ja = row_off[nodeA];
    const int ea = row_off[nodeA + 1];
    int jb = hasB ? row_off[nodeB] : 0;
    const int eb = hasB ? row_off[nodeB + 1] : 0;
    float accA0 = 0.f, accA1 = 0.f, accB0 = 0.f, accB1 = 0.f;

    while ((ja < ea) || (jb < eb)) {
      uint32_t xa[8], xb[8];
      const bool runA = ja < ea, runB = jb < eb;
      if (runA) {  // issue 8 loads for stream A
#pragma unroll
        for (int t = 0; t < 8; ++t) {
          int jj = ja + t;
          int jc = jj < ea ? jj : ea - 1;
          uint32_t sj = (uint32_t)adj[jc];
          uint32_t v = Xu[(sj << 6) + lu];
          xa[t] = (jj < ea) ? v : 0u;
        }
      }
      if (runB) {  // issue 8 more (independent -> 16 in flight)
#pragma unroll
        for (int t = 0; t < 8; ++t) {
          int jj = jb + t;
          int jc = jj < eb ? jj : eb - 1;
          uint32_t sj = (uint32_t)adj[jc];
          uint32_t v = Xu[(sj << 6) + lu];
          xb[t] = (jj < eb) ? v : 0u;
        }
      }
      if (runA) {  // depth-2 fp16 pairwise tree, fp32 accumulate
        __half2 t0 = __hadd2(as_h2(xa[0]), as_h2(xa[1]));
        __half2 t1 = __hadd2(as_h2(xa[2]), as_h2(xa[3]));
        __half2 t2 = __hadd2(as_h2(xa[4]), as_h2(xa[5]));
        __half2 t3 = __hadd2(as_h2(xa[6]), as_h2(xa[7]));
        float2 u0 = __half22float2(__hadd2(t0, t1));
        float2 u1 = __half22float2(__hadd2(t2, t3));
        accA0 += u0.x + u1.x;
        accA1 += u0.y + u1.y;
        ja += 8;
      }
      if (runB) {
        __half2 t0 = __hadd2(as_h2(xb[0]), as_h2(xb[1]));
        __half2 t1 = __hadd2(as_h2(xb[2]), as_h2(xb[3]));
        __half2 t2 = __hadd2(as_h2(xb[4]), as_h2(xb[5]));
        __half2 t3 = __hadd2(as_h2(xb[6]), as_h2(xb[7]));
        float2 u0 = __half22float2(__hadd2(t0, t1));
        float2 u1 = __half22float2(__hadd2(t2, t3));
        accB0 += u0.x + u1.x;
        accB1 += u0.y + u1.y;
        jb += 8;
      }
    }

    {  // finalize node A
      float dnn = dn[nodeA];
      float v0, v1;
      if constexpr (AFF) {
        float wsn = wsum[nodeA];
        v0 = dnn * fmaf(af0, accA0, bf0 * wsn);
        v1 = dnn * fmaf(af1, accA1, bf1 * wsn);
        __half2 hv = __floats2half2_rn(v0, v1);
        Yout[((uint32_t)nodeA << 6) + lu] = *(const uint32_t*)&hv;
      } else {
        v0 = dnn * accA0;
        v1 = dnn * accA1;
        __half2 hv = __floats2half2_rn(v0 * dnn, v1 * dnn);  // W1 = dn^2*acc
        Yout[((uint32_t)nodeA << 6) + lu] = *(const uint32_t*)&hv;
      }
      s0 += v0; s1 += v1; q0 += v0 * v0; q1 += v1 * v1;
    }
    if (hasB) {  // finalize node B
      float dnn = dn[nodeB];
      float v0, v1;
      if constexpr (AFF) {
        float wsn = wsum[nodeB];
        v0 = dnn * fmaf(af0, accB0, bf0 * wsn);
        v1 = dnn * fmaf(af1, accB1, bf1 * wsn);
        __half2 hv = __floats2half2_rn(v0, v1);
        Yout[((uint32_t)nodeB << 6) + lu] = *(const uint32_t*)&hv;
      } else {
        v0 = dnn * accB0;
        v1 = dnn * accB1;
        __half2 hv = __floats2half2_rn(v0 * dnn, v1 * dnn);
        Yout[((uint32_t)nodeB << 6) + lu] = *(const uint32_t*)&hv;
      }
      s0 += v0; s1 += v1; q0 += v0 * v0; q1 += v1 * v1;
    }
  }

  // block epilogue: LDS cross-wave reduce, then 256 lane-atomics per block
  __shared__ float red[4][256];
  red[w][l] = s0; red[w][64 + l] = s1; red[w][128 + l] = q0; red[w][192 + l] = q1;
  __syncthreads();
  float t = red[0][tid] + red[1][tid] + red[2][tid] + red[3][tid];
  int comp = tid >> 6, li = tid & 63;
  int sh = blockIdx.x & (NSH - 1);
  float* dstp = ((comp & 2) ? sqS : sumS) + sh * DIMS;
  atomicAdd(&dstp[2 * li + (comp & 1)], t);
}

// ---------------- BN affine coefficients (reduces NSH shadow copies) ----------------
__global__ void affine_k(const float* __restrict__ sum, const float* __restrict__ sq,
                         const float* __restrict__ gamma, const float* __restrict__ beta,
                         float* __restrict__ a, float* __restrict__ b, float invn) {
  int d = threadIdx.x;
  float s = 0.f, q = 0.f;
  for (int k = 0; k < NSH; ++k) { s += sum[k * DIMS + d]; q += sq[k * DIMS + d]; }
  float mu = s * invn;
  float var = q * invn - mu * mu;
  float rs = rsqrtf(var + BN_EPS);
  float ad = rs * gamma[d];
  a[d] = ad;
  b[d] = beta[d] - mu * ad;
}

// fold pre-matmul affine into weights, TRANSPOSED fp16:
// Wt[o][d] = (half)(a2[d]*W[d][o]);  cp[o] = sum_d b2[d]*W[d][o] + cb[o]
__global__ void foldw_k(const float* __restrict__ W, const float* __restrict__ cb,
                        const float* __restrict__ a2, const float* __restrict__ b2,
                        __half* __restrict__ Wt, float* __restrict__ cp) {
  int o = blockIdx.x;
  int d = threadIdx.x;
  float w = W[d * DIMS + o];
  Wt[o * DIMS + d] = __float2half(a2[d] * w);
  __shared__ float red[128];
  red[d] = b2[d] * w;
  __syncthreads();
  for (int off = 64; off > 0; off >>= 1) {
    if (d < off) red[d] += red[d + off];
    __syncthreads();
  }
  if (d == 0) cp[o] = red[0] + cb[o];
}

// ---------------- Z = X @ W + cp via MFMA (fp16 in/out, f32 accum, fused BN stats) ----
__global__ __launch_bounds__(256) void matmul_k(
    const uint4* __restrict__ X, const uint4* __restrict__ Wt,
    const float* __restrict__ cp, __half* __restrict__ Z,
    float* __restrict__ sumS, float* __restrict__ sqS, int n) {
  int tid = threadIdx.x;
  int l = tid & 63, w = tid >> 6;
  int rowg = l & 15;  // A-row / B-col / D-col within tile
  int kg = l >> 4;    // k-group
  int r0 = (blockIdx.x * 4 + w) * 16;
  bool active = r0 < n;

  __shared__ float sred[4][128], qred[4][128];
  float svals[8], qvals[8];

  if (active) {
    f32x4 acc[8] = {};
    const uint4* xrow = X + (size_t)(r0 + rowg) * 16;
    bool arow_ok = (r0 + rowg) < n;
#pragma unroll
    for (int kk = 0; kk < 4; ++kk) {
      uint4 au = arow_ok ? xrow[kk * 4 + kg] : make_uint4(0u, 0u, 0u, 0u);
      f16x8 afr = as_f16x8(au);
#pragma unroll
      for (int c = 0; c < 8; ++c) {
        f16x8 bfr = as_f16x8(Wt[(size_t)(c * 16 + rowg) * 16 + kk * 4 + kg]);
        acc[c] = __builtin_amdgcn_mfma_f32_16x16x32_f16(afr, bfr, acc[c], 0, 0, 0);
      }
    }
#pragma unroll
    for (int c = 0; c < 8; ++c) {
      float cpv = cp[c * 16 + rowg];
      float s = 0.f, q = 0.f;
#pragma unroll
      for (int r = 0; r < 4; ++r) {
        int row = r0 + kg * 4 + r;
        float vv = acc[c][r] + cpv;
        bool ok = row < n;
        vv = ok ? vv : 0.f;
        s += vv; q += vv * vv;
        if (ok) Z[(size_t)row * DIMS + c * 16 + rowg] = __float2half(vv);
      }
      s += __shfl_xor(s, 16); s += __shfl_xor(s, 32);
      q += __shfl_xor(q, 16); q += __shfl_xor(q, 32);
      svals[c] = s; qvals[c] = q;
    }
  }
  if (active) {
    if (kg == 0) {
#pragma unroll
      for (int c = 0; c < 8; ++c) {
        sred[w][c * 16 + rowg] = svals[c];
        qred[w][c * 16 + rowg] = qvals[c];
      }
    }
  } else {
    sred[w][l] = 0.f; sred[w][64 + l] = 0.f;
    qred[w][l] = 0.f; qred[w][64 + l] = 0.f;
  }
  __syncthreads();
  int f = tid & 127;
  int sh = blockIdx.x & (NSH - 1);
  if (tid < 128) {
    float s = sred[0][f] + sred[1][f] + sred[2][f] + sred[3][f];
    atomicAdd(&sumS[sh * DIMS + f], s);
  } else {
    float q = qred[0][f] + qred[1][f] + qred[2][f] + qred[3][f];
    atomicAdd(&sqS[sh * DIMS + f], q);
  }
}

// ---------------- graph segment starts (node2graph is sorted) ----------------
__global__ void gstart_k(const int* __restrict__ n2g, int* __restrict__ gstart, int n, int G) {
  int i = blockIdx.x * blockDim.x + threadIdx.x;
  if (i >= n) return;
  int g = n2g[i];
  int gp = (i == 0) ? -1 : n2g[i - 1];
  for (int x = gp + 1; x <= g; ++x) gstart[x] = i;
  if (i == n - 1) {
    for (int x = g + 1; x <= G; ++x) gstart[x] = n;
  }
}

// ---------------- BN2-apply + relu + mean-pool + 128->2 projection ----------------
__global__ __launch_bounds__(512) void pool_pred_k(
    const uint4* __restrict__ Z, const int* __restrict__ gstart,
    const float* __restrict__ a3, const float* __restrict__ b3,
    const float* __restrict__ pw, const float* __restrict__ pb,
    float* __restrict__ out) {
  int g = blockIdx.x;
  int tid = threadIdx.x;
  int l = tid & 63, w = tid >> 6;  // w 0..7
  int grp = l >> 4, fl = l & 15;
  int f0 = fl * 8;
  float av[8], bv[8];
#pragma unroll
  for (int q = 0; q < 8; ++q) { av[q] = a3[f0 + q]; bv[q] = b3[f0 + q]; }
  int s = gstart[g], e = gstart[g + 1];
  float rs[8] = {0.f, 0.f, 0.f, 0.f, 0.f, 0.f, 0.f, 0.f};
  for (int ni = s + (w * 4 + grp); ni < e; ni += 32) {
    uint4 zv = Z[(size_t)ni * 16 + fl];
    const __half2* h = (const __half2*)&zv;
#pragma unroll
    for (int q = 0; q < 4; ++q) {
      float2 z = __half22float2(h[q]);
      rs[2 * q] += fmaxf(fmaf(z.x, av[2 * q], bv[2 * q]), 0.f);
      rs[2 * q + 1] += fmaxf(fmaf(z.y, av[2 * q + 1], bv[2 * q + 1]), 0.f);
    }
  }
  float p0 = 0.f, p1 = 0.f;
#pragma unroll
  for (int q = 0; q < 8; ++q) {
    p0 += rs[q] * pw[(f0 + q) * 2 + 0];
    p1 += rs[q] * pw[(f0 + q) * 2 + 1];
  }
  __shared__ float r[2][512];
  r[0][tid] = p0; r[1][tid] = p1;
  __syncthreads();
  for (int off = 256; off > 0; off >>= 1) {
    if (tid < off) { r[0][tid] += r[0][tid + off]; r[1][tid] += r[1][tid + off]; }
    __syncthreads();
  }
  if (tid == 0) {
    float inv = 1.f / fmaxf((float)(e - s), 1.f);
    out[g * 2 + 0] = r[0][0] * inv + pb[0];
    out[g * 2 + 1] = r[1][0] * inv + pb[1];
  }
}

// ---------------- host launch ----------------
extern "C" void kernel_launch(void* const* d_in, const int* in_sizes, int n_in,
                              void* d_out, int out_size, void* d_ws, size_t ws_size,
                              hipStream_t stream) {
  const float* nfeat  = (const float*)d_in[0];
  const int*   src    = (const int*)d_in[1];
  const int*   dst    = (const int*)d_in[2];
  const int*   n2g    = (const int*)d_in[3];
  // d_in[4] = num_graphs (device scalar) — derived from out_size instead
  const float* conv_w = (const float*)d_in[5];
  const float* conv_b = (const float*)d_in[6];
  const float* gamma1 = (const float*)d_in[7];
  const float* beta1  = (const float*)d_in[8];
  const float* gamma2 = (const float*)d_in[9];
  const float* beta2  = (const float*)d_in[10];
  const float* pred_w = (const float*)d_in[11];
  const float* pred_b = (const float*)d_in[12];
  float* out = (float*)d_out;
  (void)n_in; (void)ws_size;

  const int n = in_sizes[0] / DIMS;
  const int e = in_sizes[1];
  const int g = out_size / 2;
  const int nbins = (n + 511) >> 9;  // <= 512 (n <= 262144)

  char* p = (char*)d_ws;
  auto alloc = [&](size_t bytes) { char* r = p; p += (bytes + 255) & ~(size_t)255; return r; };
  uint32_t* Xp  = (uint32_t*)alloc((size_t)n * 64 * 4);  // dn-scaled input rows (fp16)
  uint32_t* W1  = (uint32_t*)alloc((size_t)n * 64 * 4);  // dn^2-scaled h1 rows (fp16)
  uint32_t* Y2  = (uint32_t*)alloc((size_t)n * 64 * 4);  // h2 rows (fp16)
  __half*   Zh  = (__half*)alloc((size_t)n * 64 * 4);    // matmul output rows (fp16)
  float* dnorm = (float*)alloc((size_t)n * 4);
  float* stat  = (float*)alloc(((size_t)6 * NSH * DIMS + n) * 4);  // stats + wsum
  float* wsum  = stat + 6 * NSH * DIMS;
  float* affA  = (float*)alloc(3 * DIMS * 4);
  float* affB  = (float*)alloc(3 * DIMS * 4);
  __half* Wt   = (__half*)alloc(DIMS * DIMS * 2);
  float* cp    = (float*)alloc(DIMS * 4);
  int* deg     = (int*)alloc((size_t)n * 4);
  int* row_off = (int*)alloc(((size_t)n + 1) * 4);
  int* adj     = (int*)alloc((size_t)e * 4);
  int* ebin    = (int*)alloc((size_t)e * 4);
  int* Cmat    = (int*)alloc((size_t)NPB * 512 * 4);
  int* tot     = (int*)alloc(512 * 4);
  int* boff    = (int*)alloc(520 * 4);
  int* bsum    = (int*)alloc(2048 * 4);
  int* gstart  = (int*)alloc(((size_t)g + 1) * 4);

  const int SLAB = NSH * DIMS;
  float* S0 = stat + 0 * SLAB; float* Q0 = stat + 1 * SLAB;
  float* S1 = stat + 2 * SLAB; float* Q1 = stat + 3 * SLAB;
  float* S2 = stat + 4 * SLAB; float* Q2 = stat + 5 * SLAB;

  const int nb = (n + 1023) / 1024;  // <= 256 required
  const float invn = 1.0f / (float)n;
  const int nwaves = GB * 4;
  const int chunk = (e + NPB - 1) / NPB;

  // zero stats
  zero_k<<<dim3(((size_t)6 * SLAB + 255) / 256), dim3(256), 0, stream>>>(stat, (size_t)6 * SLAB);
  // two-pass binned CSR build (no global atomics)
  cnt_k<<<dim3(NPB), dim3(256), 0, stream>>>(dst, Cmat, e, chunk);
  colscan_k<<<dim3(512), dim3(512), 0, stream>>>(Cmat, tot);
  bscan_k<<<dim3(1), dim3(512), 0, stream>>>(tot, nbins, boff, e);
  scat_k<<<dim3(NPB), dim3(256), 0, stream>>>(src, dst, Cmat, boff, ebin, e, chunk);
  deg_bins_k<<<dim3(nbins), dim3(256), 0, stream>>>(ebin, boff, deg, n);
  cvt_k<<<dim3(2048), dim3(256), 0, stream>>>(nfeat, Xp, deg, dnorm, (size_t)n * 64);
  scan1_k<<<dim3(nb), dim3(256), 0, stream>>>(deg, bsum, n);
  scan2_k<<<dim3(1), dim3(256), 0, stream>>>(bsum, nb, row_off, n, e);
  scan3_k<<<dim3(nb), dim3(256), 0, stream>>>(deg, bsum, row_off, n);
  adj_bins_k<<<dim3(nbins), dim3(512), 0, stream>>>(ebin, boff, row_off, dnorm, adj, wsum, n);

  // hop 1: Xp -> W1 (stats of h1 -> S0/Q0)
  gather_k<false><<<dim3(GB), dim3(256), 0, stream>>>(
      Xp, W1, row_off, adj, dnorm, wsum, nullptr, nullptr, S0, Q0, n, nwaves);
  affine_k<<<dim3(1), dim3(DIMS), 0, stream>>>(S0, Q0, gamma1, beta1, affA + 0, affB + 0, invn);
  // hop 2: W1 -> Y2 = h2 (stats -> S1/Q1)
  gather_k<true><<<dim3(GB), dim3(256), 0, stream>>>(
      W1, Y2, row_off, adj, dnorm, wsum, affA + 0, affB + 0, S1, Q1, n, nwaves);
  affine_k<<<dim3(1), dim3(DIMS), 0, stream>>>(S1, Q1, gamma1, beta1, affA + DIMS, affB + DIMS, invn);
  // fold stage-1 affine into transposed fp16 weights, then MFMA matmul (stats -> S2/Q2)
  foldw_k<<<dim3(DIMS), dim3(DIMS), 0, stream>>>(conv_w, conv_b, affA + DIMS, affB + DIMS, Wt, cp);
  matmul_k<<<dim3((n + 63) / 64), dim3(256), 0, stream>>>(
      (const uint4*)Y2, (const uint4*)Wt, cp, Zh, S2, Q2, n);
  affine_k<<<dim3(1), dim3(DIMS), 0, stream>>>(S2, Q2, gamma2, beta2, affA + 2 * DIMS, affB + 2 * DIMS, invn);
  // pooling + prediction
  gstart_k<<<dim3((n + 255) / 256), dim3(256), 0, stream>>>(n2g, gstart, n, g);
  pool_pred_k<<<dim3(g), dim3(512), 0, stream>>>((const uint4*)Zh, gstart,
                                                 affA + 2 * DIMS, affB + 2 * DIMS,
                                                 pred_w, pred_b, out);
}

// Round 10
// 254.292 us; speedup vs baseline: 3.3717x; 1.1211x over previous
//
#include <hip/hip_runtime.h>
#include <hip/hip_fp16.h>
#include <cstddef>
#include <cstdint>

constexpr int DIMS = 128;
constexpr float BN_EPS = 1e-5f;
constexpr int NSH = 64;   // stat shadow copies
constexpr int GB = 4096;  // gather grid blocks (x4 waves = 16384 waves)
constexpr int NPB = 512;  // partition blocks for CSR build

typedef _Float16 f16x8 __attribute__((ext_vector_type(8)));
typedef float f32x4 __attribute__((ext_vector_type(4)));

static __device__ __forceinline__ f16x8 as_f16x8(uint4 u) {
  union { uint4 u; f16x8 h; } x; x.u = u; return x.h;
}
static __device__ __forceinline__ __half2 as_h2(uint32_t u) {
  union { uint32_t u; __half2 h; } x; x.u = u; return x.h;
}

// ---------------- utility ----------------
__global__ void zero_k(float* __restrict__ fp, size_t nf) {
  size_t i = (size_t)blockIdx.x * blockDim.x + threadIdx.x;
  if (i < nf) fp[i] = 0.f;
}

// fp32 -> fp16 conversion with dn pre-scale: Xp[s] = dn[s] * nfeat[s]
__global__ void cvt_k(const float* __restrict__ in, uint32_t* __restrict__ out,
                      const float* __restrict__ dnorm, size_t n64) {
  size_t i = (size_t)blockIdx.x * blockDim.x + threadIdx.x;
  size_t stride = (size_t)gridDim.x * blockDim.x;
  const float2* in2 = (const float2*)in;
  for (; i < n64; i += stride) {
    float d = dnorm[i >> 6];
    float2 v = in2[i];
    __half2 h = __floats2half2_rn(v.x * d, v.y * d);
    out[i] = *(const uint32_t*)&h;
  }
}

// ---------------- two-pass binned CSR build (no global atomics) ----------------
// bins of 512 nodes; nbins <= 512 (n <= 262144). C layout: C[block*512 + bin].

// per-block histogram of its contiguous edge chunk -> C[block][bin]
__global__ __launch_bounds__(256) void cnt_k(const int* __restrict__ dst,
                                             int* __restrict__ C, int e, int chunk) {
  __shared__ int hist[512];
  int b = blockIdx.x;
  for (int j = threadIdx.x; j < 512; j += 256) hist[j] = 0;
  __syncthreads();
  int i0 = b * chunk;
  int i1 = i0 + chunk; if (i1 > e) i1 = e;
  for (int i = i0 + threadIdx.x; i < i1; i += 256)
    atomicAdd(&hist[dst[i] >> 9], 1);
  __syncthreads();
  for (int j = threadIdx.x; j < 512; j += 256) C[b * 512 + j] = hist[j];
}

// one block PER BIN: exclusive scan down the bin's column of C; emits per-bin total
__global__ __launch_bounds__(512) void colscan_k(int* __restrict__ C, int* __restrict__ tot) {
  int j = blockIdx.x;   // bin
  int t = threadIdx.x;  // partition block
  int v = C[t * 512 + j];
  __shared__ int lds[512];
  lds[t] = v; __syncthreads();
  for (int off = 1; off < 512; off <<= 1) {
    int add = (t >= off) ? lds[t - off] : 0;
    __syncthreads();
    lds[t] += add;
    __syncthreads();
  }
  C[t * 512 + j] = lds[t] - v;  // exclusive within-column prefix
  if (t == 511) tot[j] = lds[511];
}

// single block: exclusive scan of per-bin totals -> boff
__global__ __launch_bounds__(512) void bscan_k(const int* __restrict__ tot, int nbins,
                                               int* __restrict__ boff, int e) {
  int t = threadIdx.x;
  int v = tot[t];
  __shared__ int lds[512];
  lds[t] = v; __syncthreads();
  for (int off = 1; off < 512; off <<= 1) {
    int add = (t >= off) ? lds[t - off] : 0;
    __syncthreads();
    lds[t] += add;
    __syncthreads();
  }
  boff[t] = lds[t] - v;
  if (t == 0) boff[nbins] = e;
}

// scatter edges to bin-grouped ebin using LDS-only cursors
// ebin[p] = (src<<9) | (dst&511)   (src < 2^18 fits 27 bits)
__global__ __launch_bounds__(256) void scat_k(const int* __restrict__ src,
                                              const int* __restrict__ dst,
                                              const int* __restrict__ C,
                                              const int* __restrict__ boff,
                                              int* __restrict__ ebin, int e, int chunk) {
  __shared__ int cur[512];
  int b = blockIdx.x;
  for (int j = threadIdx.x; j < 512; j += 256) cur[j] = boff[j] + C[b * 512 + j];
  __syncthreads();
  int i0 = b * chunk;
  int i1 = i0 + chunk; if (i1 > e) i1 = e;
  for (int i = i0 + threadIdx.x; i < i1; i += 256) {
    int d = dst[i];
    int bin = d >> 9;
    int p = atomicAdd(&cur[bin], 1);
    ebin[p] = (src[i] << 9) | (d & 511);
  }
}

// fused per-bin: degree histogram -> LDS scan -> row_off + dnorm
__global__ __launch_bounds__(512) void binidx_k(
    const int* __restrict__ ebin, const int* __restrict__ boff,
    int* __restrict__ row_off, float* __restrict__ dnorm, int n, int nbins) {
  __shared__ int cnt[512];
  __shared__ int scn[512];
  int b = blockIdx.x;
  int t = threadIdx.x;
  cnt[t] = 0;
  __syncthreads();
  int j0 = boff[b], j1 = boff[b + 1];
  for (int i = j0 + t; i < j1; i += 512) atomicAdd(&cnt[ebin[i] & 511], 1);
  __syncthreads();
  int v = cnt[t];
  scn[t] = v; __syncthreads();
  for (int off = 1; off < 512; off <<= 1) {
    int add = (t >= off) ? scn[t - off] : 0;
    __syncthreads();
    scn[t] += add;
    __syncthreads();
  }
  int node = (b << 9) + t;
  if (node < n) {
    row_off[node] = j0 + scn[t] - v;
    dnorm[node] = rsqrtf(fmaxf((float)v, 1.0f));
  }
  if (b == nbins - 1 && t == 0) row_off[n] = j1;  // j1 == e for last bin
}

// adj placement (bin-local, L2-hot) + wsum[node] = sum dn[src] via LDS accumulators
__global__ __launch_bounds__(512) void adj_bins_k(
    const int* __restrict__ ebin, const int* __restrict__ boff,
    const int* __restrict__ row_off, const float* __restrict__ dnorm,
    int* __restrict__ adj, float* __restrict__ wsum, int n) {
  __shared__ int cur[512];
  __shared__ int ro[512];
  __shared__ float ws[512];
  int b = blockIdx.x;
  int base = b << 9;
  int t = threadIdx.x;
  {
    cur[t] = 0;
    ws[t] = 0.f;
    int node = base + t;
    ro[t] = (node < n) ? row_off[node] : 0;
  }
  __syncthreads();
  int j0 = boff[b], j1 = boff[b + 1];
  for (int i = j0 + t; i < j1; i += 512) {
    int pk = ebin[i];
    int dl = pk & 511;
    int s = pk >> 9;
    int p = atomicAdd(&cur[dl], 1);
    adj[ro[dl] + p] = s;
    atomicAdd(&ws[dl], dnorm[s]);
  }
  __syncthreads();
  {
    int node = base + t;
    if (node < n) wsum[node] = ws[t];
  }
}

// ---------------- propagation hop: grid-stride, TWO nodes per wave in flight -------
// Lane owns 2 features (half2 row element). 8-deep edge pipeline per node stream.
// AFF=false (hop1): acc = sum Xp[s]; v = dn*acc (stats); store W1 = dn*v = dn^2*acc.
// AFF=true  (hop2): acc = sum W1[s]; v = dn*(a*acc + b*wsum[n]) (stats); store v.
template <bool AFF>
__global__ __launch_bounds__(256) void gather_k(
    const uint32_t* __restrict__ Xu, uint32_t* __restrict__ Yout,
    const int* __restrict__ row_off, const int* __restrict__ adj,
    const float* __restrict__ dn, const float* __restrict__ wsum,
    const float* __restrict__ a, const float* __restrict__ b,
    float* __restrict__ sumS, float* __restrict__ sqS, int n, int nwaves) {
  int tid = threadIdx.x;
  int l = tid & 63, w = tid >> 6;
  int wid = blockIdx.x * 4 + w;  // wave-uniform
  uint32_t lu = (uint32_t)l;
  int f0 = 2 * l;
  float af0 = 1.f, bf0 = 0.f, af1 = 1.f, bf1 = 0.f;
  if (AFF) { af0 = a[f0]; bf0 = b[f0]; af1 = a[f0 + 1]; bf1 = b[f0 + 1]; }
  float s0 = 0.f, s1 = 0.f, q0 = 0.f, q1 = 0.f;

  for (int nodeA = wid; nodeA < n; nodeA += 2 * nwaves) {
    const int nodeB = nodeA + nwaves;
    const bool hasB = nodeB < n;
    int ja = row_off[nodeA];
    const int ea = row_off[nodeA + 1];
    int jb = hasB ? row_off[nodeB] : 0;
    const int eb = hasB ? row_off[nodeB + 1] : 0;
    float accA0 = 0.f, accA1 = 0.f, accB0 = 0.f, accB1 = 0.f;

    while ((ja < ea) || (jb < eb)) {
      uint32_t xa[8], xb[8];
      const bool runA = ja < ea, runB = jb < eb;
      if (runA) {  // issue 8 loads for stream A
#pragma unroll
        for (int t = 0; t < 8; ++t) {
          int jj = ja + t;
          int jc = jj < ea ? jj : ea - 1;
          uint32_t sj = (uint32_t)adj[jc];
          uint32_t v = Xu[(sj << 6) + lu];
          xa[t] = (jj < ea) ? v : 0u;
        }
      }
      if (runB) {  // issue 8 more (independent -> 16 in flight)
#pragma unroll
        for (int t = 0; t < 8; ++t) {
          int jj = jb + t;
          int jc = jj < eb ? jj : eb - 1;
          uint32_t sj = (uint32_t)adj[jc];
          uint32_t v = Xu[(sj << 6) + lu];
          xb[t] = (jj < eb) ? v : 0u;
        }
      }
      if (runA) {  // depth-2 fp16 pairwise tree, fp32 accumulate
        __half2 t0 = __hadd2(as_h2(xa[0]), as_h2(xa[1]));
        __half2 t1 = __hadd2(as_h2(xa[2]), as_h2(xa[3]));
        __half2 t2 = __hadd2(as_h2(xa[4]), as_h2(xa[5]));
        __half2 t3 = __hadd2(as_h2(xa[6]), as_h2(xa[7]));
        float2 u0 = __half22float2(__hadd2(t0, t1));
        float2 u1 = __half22float2(__hadd2(t2, t3));
        accA0 += u0.x + u1.x;
        accA1 += u0.y + u1.y;
        ja += 8;
      }
      if (runB) {
        __half2 t0 = __hadd2(as_h2(xb[0]), as_h2(xb[1]));
        __half2 t1 = __hadd2(as_h2(xb[2]), as_h2(xb[3]));
        __half2 t2 = __hadd2(as_h2(xb[4]), as_h2(xb[5]));
        __half2 t3 = __hadd2(as_h2(xb[6]), as_h2(xb[7]));
        float2 u0 = __half22float2(__hadd2(t0, t1));
        float2 u1 = __half22float2(__hadd2(t2, t3));
        accB0 += u0.x + u1.x;
        accB1 += u0.y + u1.y;
        jb += 8;
      }
    }

    {  // finalize node A
      float dnn = dn[nodeA];
      float v0, v1;
      if constexpr (AFF) {
        float wsn = wsum[nodeA];
        v0 = dnn * fmaf(af0, accA0, bf0 * wsn);
        v1 = dnn * fmaf(af1, accA1, bf1 * wsn);
        __half2 hv = __floats2half2_rn(v0, v1);
        Yout[((uint32_t)nodeA << 6) + lu] = *(const uint32_t*)&hv;
      } else {
        v0 = dnn * accA0;
        v1 = dnn * accA1;
        __half2 hv = __floats2half2_rn(v0 * dnn, v1 * dnn);  // W1 = dn^2*acc
        Yout[((uint32_t)nodeA << 6) + lu] = *(const uint32_t*)&hv;
      }
      s0 += v0; s1 += v1; q0 += v0 * v0; q1 += v1 * v1;
    }
    if (hasB) {  // finalize node B
      float dnn = dn[nodeB];
      float v0, v1;
      if constexpr (AFF) {
        float wsn = wsum[nodeB];
        v0 = dnn * fmaf(af0, accB0, bf0 * wsn);
        v1 = dnn * fmaf(af1, accB1, bf1 * wsn);
        __half2 hv = __floats2half2_rn(v0, v1);
        Yout[((uint32_t)nodeB << 6) + lu] = *(const uint32_t*)&hv;
      } else {
        v0 = dnn * accB0;
        v1 = dnn * accB1;
        __half2 hv = __floats2half2_rn(v0 * dnn, v1 * dnn);
        Yout[((uint32_t)nodeB << 6) + lu] = *(const uint32_t*)&hv;
      }
      s0 += v0; s1 += v1; q0 += v0 * v0; q1 += v1 * v1;
    }
  }

  // block epilogue: LDS cross-wave reduce, then 256 lane-atomics per block
  __shared__ float red[4][256];
  red[w][l] = s0; red[w][64 + l] = s1; red[w][128 + l] = q0; red[w][192 + l] = q1;
  __syncthreads();
  float t = red[0][tid] + red[1][tid] + red[2][tid] + red[3][tid];
  int comp = tid >> 6, li = tid & 63;
  int sh = blockIdx.x & (NSH - 1);
  float* dstp = ((comp & 2) ? sqS : sumS) + sh * DIMS;
  atomicAdd(&dstp[2 * li + (comp & 1)], t);
}

// ---------------- BN affine coefficients (reduces NSH shadow copies) ----------------
__global__ void affine_k(const float* __restrict__ sum, const float* __restrict__ sq,
                         const float* __restrict__ gamma, const float* __restrict__ beta,
                         float* __restrict__ a, float* __restrict__ b, float invn) {
  int d = threadIdx.x;
  float s = 0.f, q = 0.f;
  for (int k = 0; k < NSH; ++k) { s += sum[k * DIMS + d]; q += sq[k * DIMS + d]; }
  float mu = s * invn;
  float var = q * invn - mu * mu;
  float rs = rsqrtf(var + BN_EPS);
  float ad = rs * gamma[d];
  a[d] = ad;
  b[d] = beta[d] - mu * ad;
}

// fold pre-matmul affine into weights, TRANSPOSED fp16:
// Wt[o][d] = (half)(a2[d]*W[d][o]);  cp[o] = sum_d b2[d]*W[d][o] + cb[o]
__global__ void foldw_k(const float* __restrict__ W, const float* __restrict__ cb,
                        const float* __restrict__ a2, const float* __restrict__ b2,
                        __half* __restrict__ Wt, float* __restrict__ cp) {
  int o = blockIdx.x;
  int d = threadIdx.x;
  float w = W[d * DIMS + o];
  Wt[o * DIMS + d] = __float2half(a2[d] * w);
  __shared__ float red[128];
  red[d] = b2[d] * w;
  __syncthreads();
  for (int off = 64; off > 0; off >>= 1) {
    if (d < off) red[d] += red[d + off];
    __syncthreads();
  }
  if (d == 0) cp[o] = red[0] + cb[o];
}

// ---------------- Z = X @ W + cp via MFMA, 32 rows/wave, LDS-staged stores ----------
// A: lane row=l&15 (+16 for group 1), k=(l>>4)*8+j.  B from Wt[o][d] row-contig.
// C/D: col=l&15, row=(l>>4)*4+reg.  Output staged in padded LDS -> uint4 stores.
__global__ __launch_bounds__(256) void matmul_k(
    const uint4* __restrict__ X, const uint4* __restrict__ Wt,
    const float* __restrict__ cp, uint4* __restrict__ Z,
    float* __restrict__ sumS, float* __restrict__ sqS, int n) {
  int tid = threadIdx.x;
  int l = tid & 63, w = tid >> 6;
  int rowg = l & 15;  // A-row / B-col / D-col within tile
  int kg = l >> 4;    // k-group
  int r0 = (blockIdx.x * 4 + w) * 32;
  bool active = r0 < n;

  __shared__ __half outs[4][16][136];  // per-wave staging, +8 halves row pad
  __shared__ float sred[4][128], qred[4][128];
  float svals[8], qvals[8];

  if (active) {
    f32x4 acc0[8] = {}, acc1[8] = {};
    const uint4* xr0 = X + (size_t)(r0 + rowg) * 16;
    const uint4* xr1 = X + (size_t)(r0 + 16 + rowg) * 16;
    bool ok0 = (r0 + rowg) < n;
    bool ok1 = (r0 + 16 + rowg) < n;
#pragma unroll
    for (int kk = 0; kk < 4; ++kk) {
      uint4 au0 = ok0 ? xr0[kk * 4 + kg] : make_uint4(0u, 0u, 0u, 0u);
      uint4 au1 = ok1 ? xr1[kk * 4 + kg] : make_uint4(0u, 0u, 0u, 0u);
      f16x8 a0 = as_f16x8(au0), a1 = as_f16x8(au1);
#pragma unroll
      for (int c = 0; c < 8; ++c) {
        f16x8 bfr = as_f16x8(Wt[(size_t)(c * 16 + rowg) * 16 + kk * 4 + kg]);
        acc0[c] = __builtin_amdgcn_mfma_f32_16x16x32_f16(a0, bfr, acc0[c], 0, 0, 0);
        acc1[c] = __builtin_amdgcn_mfma_f32_16x16x32_f16(a1, bfr, acc1[c], 0, 0, 0);
      }
    }
#pragma unroll
    for (int c = 0; c < 8; ++c) { svals[c] = 0.f; qvals[c] = 0.f; }
#pragma unroll
    for (int gidx = 0; gidx < 2; ++gidx) {
      int rbase = r0 + gidx * 16;
#pragma unroll
      for (int c = 0; c < 8; ++c) {
        float cpv = cp[c * 16 + rowg];
        f32x4 av = (gidx == 0) ? acc0[c] : acc1[c];
#pragma unroll
        for (int r = 0; r < 4; ++r) {
          int row = rbase + kg * 4 + r;
          float vv = av[r] + cpv;
          vv = (row < n) ? vv : 0.f;
          svals[c] += vv; qvals[c] += vv * vv;
          outs[w][kg * 4 + r][c * 16 + rowg] = __float2half(vv);
        }
      }
      // coalesced store of this 16-row group (wave-local LDS, in-order per wave)
#pragma unroll
      for (int it = 0; it < 4; ++it) {
        int lr = it * 4 + kg;
        int grow = rbase + lr;
        if (grow < n)
          Z[(size_t)grow * 16 + rowg] = *(const uint4*)&outs[w][lr][rowg * 8];
      }
    }
#pragma unroll
    for (int c = 0; c < 8; ++c) {
      svals[c] += __shfl_xor(svals[c], 16); svals[c] += __shfl_xor(svals[c], 32);
      qvals[c] += __shfl_xor(qvals[c], 16); qvals[c] += __shfl_xor(qvals[c], 32);
    }
  }
  if (active) {
    if (kg == 0) {
#pragma unroll
      for (int c = 0; c < 8; ++c) {
        sred[w][c * 16 + rowg] = svals[c];
        qred[w][c * 16 + rowg] = qvals[c];
      }
    }
  } else {
    sred[w][l] = 0.f; sred[w][64 + l] = 0.f;
    qred[w][l] = 0.f; qred[w][64 + l] = 0.f;
  }
  __syncthreads();
  int f = tid & 127;
  int sh = blockIdx.x & (NSH - 1);
  if (tid < 128) {
    float s = sred[0][f] + sred[1][f] + sred[2][f] + sred[3][f];
    atomicAdd(&sumS[sh * DIMS + f], s);
  } else {
    float q = qred[0][f] + qred[1][f] + qred[2][f] + qred[3][f];
    atomicAdd(&sqS[sh * DIMS + f], q);
  }
}

// ---------------- graph segment starts (node2graph is sorted) ----------------
__global__ void gstart_k(const int* __restrict__ n2g, int* __restrict__ gstart, int n, int G) {
  int i = blockIdx.x * blockDim.x + threadIdx.x;
  if (i >= n) return;
  int g = n2g[i];
  int gp = (i == 0) ? -1 : n2g[i - 1];
  for (int x = gp + 1; x <= g; ++x) gstart[x] = i;
  if (i == n - 1) {
    for (int x = g + 1; x <= G; ++x) gstart[x] = n;
  }
}

// ---------------- BN2-apply + relu + mean-pool + 128->2 projection ----------------
__global__ __launch_bounds__(512) void pool_pred_k(
    const uint4* __restrict__ Z, const int* __restrict__ gstart,
    const float* __restrict__ a3, const float* __restrict__ b3,
    const float* __restrict__ pw, const float* __restrict__ pb,
    float* __restrict__ out) {
  int g = blockIdx.x;
  int tid = threadIdx.x;
  int l = tid & 63, w = tid >> 6;  // w 0..7
  int grp = l >> 4, fl = l & 15;
  int f0 = fl * 8;
  float av[8], bv[8];
#pragma unroll
  for (int q = 0; q < 8; ++q) { av[q] = a3[f0 + q]; bv[q] = b3[f0 + q]; }
  int s = gstart[g], e = gstart[g + 1];
  float rs[8] = {0.f, 0.f, 0.f, 0.f, 0.f, 0.f, 0.f, 0.f};
  for (int ni = s + (w * 4 + grp); ni < e; ni += 32) {
    uint4 zv = Z[(size_t)ni * 16 + fl];
    const __half2* h = (const __half2*)&zv;
#pragma unroll
    for (int q = 0; q < 4; ++q) {
      float2 z = __half22float2(h[q]);
      rs[2 * q] += fmaxf(fmaf(z.x, av[2 * q], bv[2 * q]), 0.f);
      rs[2 * q + 1] += fmaxf(fmaf(z.y, av[2 * q + 1], bv[2 * q + 1]), 0.f);
    }
  }
  float p0 = 0.f, p1 = 0.f;
#pragma unroll
  for (int q = 0; q < 8; ++q) {
    p0 += rs[q] * pw[(f0 + q) * 2 + 0];
    p1 += rs[q] * pw[(f0 + q) * 2 + 1];
  }
  __shared__ float r[2][512];
  r[0][tid] = p0; r[1][tid] = p1;
  __syncthreads();
  for (int off = 256; off > 0; off >>= 1) {
    if (tid < off) { r[0][tid] += r[0][tid + off]; r[1][tid] += r[1][tid + off]; }
    __syncthreads();
  }
  if (tid == 0) {
    float inv = 1.f / fmaxf((float)(e - s), 1.f);
    out[g * 2 + 0] = r[0][0] * inv + pb[0];
    out[g * 2 + 1] = r[1][0] * inv + pb[1];
  }
}

// ---------------- host launch ----------------
extern "C" void kernel_launch(void* const* d_in, const int* in_sizes, int n_in,
                              void* d_out, int out_size, void* d_ws, size_t ws_size,
                              hipStream_t stream) {
  const float* nfeat  = (const float*)d_in[0];
  const int*   src    = (const int*)d_in[1];
  const int*   dst    = (const int*)d_in[2];
  const int*   n2g    = (const int*)d_in[3];
  // d_in[4] = num_graphs (device scalar) — derived from out_size instead
  const float* conv_w = (const float*)d_in[5];
  const float* conv_b = (const float*)d_in[6];
  const float* gamma1 = (const float*)d_in[7];
  const float* beta1  = (const float*)d_in[8];
  const float* gamma2 = (const float*)d_in[9];
  const float* beta2  = (const float*)d_in[10];
  const float* pred_w = (const float*)d_in[11];
  const float* pred_b = (const float*)d_in[12];
  float* out = (float*)d_out;
  (void)n_in; (void)ws_size;

  const int n = in_sizes[0] / DIMS;
  const int e = in_sizes[1];
  const int g = out_size / 2;
  const int nbins = (n + 511) >> 9;  // <= 512 (n <= 262144)

  char* p = (char*)d_ws;
  auto alloc = [&](size_t bytes) { char* r = p; p += (bytes + 255) & ~(size_t)255; return r; };
  uint32_t* Xp  = (uint32_t*)alloc((size_t)n * 64 * 4);  // dn-scaled input rows (fp16)
  uint32_t* W1  = (uint32_t*)alloc((size_t)n * 64 * 4);  // dn^2-scaled h1 rows (fp16)
  uint32_t* Y2  = (uint32_t*)alloc((size_t)n * 64 * 4);  // h2 rows (fp16)
  __half*   Zh  = (__half*)alloc((size_t)n * 64 * 4);    // matmul output rows (fp16)
  float* dnorm = (float*)alloc((size_t)n * 4);
  float* stat  = (float*)alloc(((size_t)6 * NSH * DIMS + n) * 4);  // stats + wsum
  float* wsum  = stat + 6 * NSH * DIMS;
  float* affA  = (float*)alloc(3 * DIMS * 4);
  float* affB  = (float*)alloc(3 * DIMS * 4);
  __half* Wt   = (__half*)alloc(DIMS * DIMS * 2);
  float* cp    = (float*)alloc(DIMS * 4);
  int* row_off = (int*)alloc(((size_t)n + 1) * 4);
  int* adj     = (int*)alloc((size_t)e * 4);
  int* ebin    = (int*)alloc((size_t)e * 4);
  int* Cmat    = (int*)alloc((size_t)NPB * 512 * 4);
  int* tot     = (int*)alloc(512 * 4);
  int* boff    = (int*)alloc(520 * 4);
  int* gstart  = (int*)alloc(((size_t)g + 1) * 4);

  const int SLAB = NSH * DIMS;
  float* S0 = stat + 0 * SLAB; float* Q0 = stat + 1 * SLAB;
  float* S1 = stat + 2 * SLAB; float* Q1 = stat + 3 * SLAB;
  float* S2 = stat + 4 * SLAB; float* Q2 = stat + 5 * SLAB;

  const float invn = 1.0f / (float)n;
  const int nwaves = GB * 4;
  const int chunk = (e + NPB - 1) / NPB;

  // zero stats
  zero_k<<<dim3(((size_t)6 * SLAB + 255) / 256), dim3(256), 0, stream>>>(stat, (size_t)6 * SLAB);
  // two-pass binned CSR build (no global atomics)
  cnt_k<<<dim3(NPB), dim3(256), 0, stream>>>(dst, Cmat, e, chunk);
  colscan_k<<<dim3(512), dim3(512), 0, stream>>>(Cmat, tot);
  bscan_k<<<dim3(1), dim3(512), 0, stream>>>(tot, nbins, boff, e);
  scat_k<<<dim3(NPB), dim3(256), 0, stream>>>(src, dst, Cmat, boff, ebin, e, chunk);
  binidx_k<<<dim3(nbins), dim3(512), 0, stream>>>(ebin, boff, row_off, dnorm, n, nbins);
  cvt_k<<<dim3(2048), dim3(256), 0, stream>>>(nfeat, Xp, dnorm, (size_t)n * 64);
  adj_bins_k<<<dim3(nbins), dim3(512), 0, stream>>>(ebin, boff, row_off, dnorm, adj, wsum, n);

  // hop 1: Xp -> W1 (stats of h1 -> S0/Q0)
  gather_k<false><<<dim3(GB), dim3(256), 0, stream>>>(
      Xp, W1, row_off, adj, dnorm, wsum, nullptr, nullptr, S0, Q0, n, nwaves);
  affine_k<<<dim3(1), dim3(DIMS), 0, stream>>>(S0, Q0, gamma1, beta1, affA + 0, affB + 0, invn);
  // hop 2: W1 -> Y2 = h2 (stats -> S1/Q1)
  gather_k<true><<<dim3(GB), dim3(256), 0, stream>>>(
      W1, Y2, row_off, adj, dnorm, wsum, affA + 0, affB + 0, S1, Q1, n, nwaves);
  affine_k<<<dim3(1), dim3(DIMS), 0, stream>>>(S1, Q1, gamma1, beta1, affA + DIMS, affB + DIMS, invn);
  // fold stage-1 affine into transposed fp16 weights, then MFMA matmul (stats -> S2/Q2)
  foldw_k<<<dim3(DIMS), dim3(DIMS), 0, stream>>>(conv_w, conv_b, affA + DIMS, affB + DIMS, Wt, cp);
  matmul_k<<<dim3((n + 127) / 128), dim3(256), 0, stream>>>(
      (const uint4*)Y2, (const uint4*)Wt, cp, (uint4*)Zh, S2, Q2, n);
  affine_k<<<dim3(1), dim3(DIMS), 0, stream>>>(S2, Q2, gamma2, beta2, affA + 2 * DIMS, affB + 2 * DIMS, invn);
  // pooling + prediction
  gstart_k<<<dim3((n + 255) / 256), dim3(256), 0, stream>>>(n2g, gstart, n, g);
  pool_pred_k<<<dim3(g), dim3(512), 0, stream>>>((const uint4*)Zh, gstart,
                                                 affA + 2 * DIMS, affB + 2 * DIMS,
                                                 pred_w, pred_b, out);
}